// Round 1
// baseline (914.594 us; speedup 1.0000x reference)
//
#include <hip/hip_runtime.h>
#include <stdint.h>

#define Bn 64
#define Tn 400
#define Hn 512
#define En 256
#define Vn 50000
#define NOOVn 100
#define TPn 50
#define H2n 1024
#define VEXTn (Vn+NOOVn)  // 50100

typedef __bf16 bf16x8 __attribute__((ext_vector_type(8)));
typedef float  f32x4  __attribute__((ext_vector_type(4)));

__device__ __forceinline__ float sigf(float x){ return 1.0f/(1.0f+__expf(-x)); }
__device__ __forceinline__ float tanh_fast(float x){
  float e = __expf(2.0f*x);
  return (e-1.0f)/(e+1.0f);
}

__device__ __forceinline__ unsigned short f2bf(float f){
  union { float f; uint32_t u; } v; v.f = f;
  uint32_t r = v.u + 0x7FFFu + ((v.u >> 16) & 1u);
  return (unsigned short)(r >> 16);
}
__device__ __forceinline__ float bf2f(unsigned short s){
  union { uint32_t u; float f; } v; v.u = ((uint32_t)s) << 16;
  return v.f;
}

__device__ __forceinline__ void async16(const void* g, void* l){
  __builtin_amdgcn_global_load_lds((__attribute__((address_space(1))) void*)g,
                                   (__attribute__((address_space(3))) void*)l, 16, 0, 0);
}

// ---------------- conversions ----------------
__global__ __launch_bounds__(256) void k_conv_enc(const float* __restrict__ enc, unsigned short* __restrict__ out){
  int i = blockIdx.x*256 + threadIdx.x;
  const float4* e4 = (const float4*)enc;
  float4 v = e4[i];
  ushort4 r;
  r.x = f2bf(v.x); r.y = f2bf(v.y); r.z = f2bf(v.z); r.w = f2bf(v.w);
  ((ushort4*)out)[i] = r;
}

// Bt[n][k] = W[k][n], n<1024 from W1 (We_h), n>=1024 from W2 (Ws_h)
__global__ __launch_bounds__(256) void k_transpose(const float* __restrict__ W1, const float* __restrict__ W2,
                                                   unsigned short* __restrict__ Bt){
  const float* W = blockIdx.z ? W2 : W1;
  int nbase = blockIdx.z * 1024;
  __shared__ float tile[32][33];
  int k0 = blockIdx.y*32, n0 = blockIdx.x*32;
  int tx = threadIdx.x & 31, ty = threadIdx.x >> 5;  // ty 0..7
  for (int i = 0; i < 32; i += 8)
    tile[ty+i][tx] = W[(size_t)(k0+ty+i)*1024 + n0+tx];
  __syncthreads();
  for (int i = 0; i < 32; i += 8)
    Bt[(size_t)(nbase+n0+ty+i)*1024 + k0+tx] = f2bf(tile[tx][ty+i]);
}

// ---------------- split-K GEMV chain (M=64, fp32 atomics) ----------------
__global__ __launch_bounds__(256) void k_gemv_x(const float* __restrict__ x_t, const float* __restrict__ ct_e,
                                                const float* __restrict__ W_xc, float* __restrict__ x_acc){
  int n = threadIdx.x;
  int b = blockIdx.y;
  int k0 = blockIdx.z*256;        // z 0..4 (K=1280)
  float acc = 0.f;
  #pragma unroll 4
  for (int kk = 0; kk < 256; ++kk){
    int k = k0 + kk;
    float a = (k < 256) ? x_t[b*256+k] : ct_e[b*1024 + k - 256];
    acc += a * W_xc[(size_t)k*256 + n];
  }
  atomicAdd(&x_acc[b*256+n], acc);
}

__global__ __launch_bounds__(256) void k_gemv_gates(const float* __restrict__ x_acc, const float* __restrict__ b_xc,
                                                    const float* __restrict__ s_h,
                                                    const float* __restrict__ W_ih, const float* __restrict__ W_hh,
                                                    float* __restrict__ gates_acc){
  int n = blockIdx.x*256 + threadIdx.x;  // 0..2047
  int b = blockIdx.y;
  int k0 = blockIdx.z*256;               // z 0..2 (K=768)
  float acc = 0.f;
  #pragma unroll 4
  for (int kk = 0; kk < 256; ++kk){
    int k = k0 + kk;
    float a; const float* wrow;
    if (k < 256){ a = x_acc[b*256+k] + b_xc[k]; wrow = &W_ih[(size_t)k*2048]; }
    else        { a = s_h[b*512 + k-256];       wrow = &W_hh[(size_t)(k-256)*2048]; }
    acc += a * wrow[n];
  }
  atomicAdd(&gates_acc[(size_t)b*2048 + n], acc);
}

__global__ __launch_bounds__(256) void k_lstm_act(const float* __restrict__ gates_acc,
                                                  const float* __restrict__ b_ih, const float* __restrict__ b_hh,
                                                  const float* __restrict__ s_c,
                                                  float* __restrict__ h_out, float* __restrict__ c_out){
  int b = blockIdx.y;
  int j = blockIdx.x*256 + threadIdx.x;
  const float* g = &gates_acc[(size_t)b*2048];
  float gi = g[j]      + b_ih[j]      + b_hh[j];
  float gf = g[512+j]  + b_ih[512+j]  + b_hh[512+j];
  float gg = g[1024+j] + b_ih[1024+j] + b_hh[1024+j];
  float go = g[1536+j] + b_ih[1536+j] + b_hh[1536+j];
  float c = sigf(gf)*s_c[b*512+j] + sigf(gi)*tanh_fast(gg);
  float h = sigf(go)*tanh_fast(c);
  h_out[b*512+j] = h;
  c_out[b*512+j] = c;
}

__global__ __launch_bounds__(256) void k_gemv_qe(const float* __restrict__ h, const float* __restrict__ c,
                                                 const float* __restrict__ We_s, float* __restrict__ qe_acc){
  int n = blockIdx.x*256 + threadIdx.x;
  int b = blockIdx.y;
  int k0 = blockIdx.z*256;
  float acc = 0.f;
  #pragma unroll 4
  for (int kk = 0; kk < 256; ++kk){
    int k = k0 + kk;
    float a = (k < 512) ? h[b*512+k] : c[b*512 + k-512];
    acc += a * We_s[(size_t)k*1024 + n];
  }
  atomicAdd(&qe_acc[b*1024+n], acc);
}

__global__ __launch_bounds__(256) void k_gemv_qd(const float* __restrict__ h, const float* __restrict__ Wd_s,
                                                 float* __restrict__ qd_acc){
  int n = blockIdx.x*256 + threadIdx.x;
  int b = blockIdx.y;
  int k0 = blockIdx.z*256;
  float acc = 0.f;
  #pragma unroll 4
  for (int kk = 0; kk < 256; ++kk){
    int k = k0 + kk;
    acc += h[b*512+k] * Wd_s[(size_t)k*512 + n];
  }
  atomicAdd(&qd_acc[b*512+n], acc);
}

__global__ __launch_bounds__(256) void k_gemv_outvec(const float* __restrict__ h, const float* __restrict__ cte,
                                                     const float* __restrict__ ctd, const float* __restrict__ et2,
                                                     const float* __restrict__ W_V, float* __restrict__ ov_acc){
  int n = blockIdx.x*256 + threadIdx.x;
  int b = blockIdx.y;
  int z = blockIdx.z;
  const float* base;
  switch(z){
    case 0:  base = &h[b*512];        break;
    case 1:  base = &cte[b*1024];     break;
    case 2:  base = &cte[b*1024+512]; break;
    case 3:  base = &ctd[b*512];      break;
    case 4:  base = &et2[b*1024];     break;
    default: base = &et2[b*1024+512]; break;
  }
  const float* wrow = &W_V[(size_t)z*512*512];
  float acc = 0.f;
  #pragma unroll 4
  for (int kk = 0; kk < 512; ++kk)
    acc += base[kk] * wrow[(size_t)kk*512 + n];
  atomicAdd(&ov_acc[b*512+n], acc);
}

__global__ __launch_bounds__(256) void k_outvec_fin(const float* __restrict__ ov_acc, const float* __restrict__ b_V,
                                                    unsigned short* __restrict__ out_vec_bf){
  int i = blockIdx.x*256 + threadIdx.x;
  int j = i & 511;
  out_vec_bf[i] = f2bf(ov_acc[i] + b_V[j]);
}

// ---------------- the big fused dual-GEMM ----------------
// 256x256 8-phase schedule (T3+T4 counted vmcnt, T5 setprio, T1 XCD swizzle).
// BK=64, 8 waves (2M x 4N), 128KB double-buffered LDS, per-wave 128x64 output.
// LDS swizzle: slot (row, chunk j) holds global 16B chunk j ^ (row&7); staged via
// inverse-swizzled GLOBAL source + linear gload_lds dest (rule 21), read back with
// the same XOR. Carried over from the verified 128^2 kernel (bank conflicts = 0).

template<int BUF, int QM>
__device__ __forceinline__ void ld_a(const unsigned short* As, bf16x8 (&a)[4][2],
                                     int wr, int lr, int lq){
#pragma unroll
  for (int mt = 0; mt < 4; ++mt){
    const int row = wr*128 + QM*64 + mt*16 + lr;
#pragma unroll
    for (int kk = 0; kk < 2; ++kk)
      a[mt][kk] = *(const bf16x8*)&As[BUF*16384 + row*64 + (((kk*4+lq) ^ (lr&7))*8)];
  }
}

template<int BUF, int QN>
__device__ __forceinline__ void ld_b(const unsigned short* Bs, bf16x8 (&b)[4][2],
                                     int wc, int lr, int lq){
#pragma unroll
  for (int nt = 0; nt < 2; ++nt){
    const int row = wc*64 + (QN*2+nt)*16 + lr;
#pragma unroll
    for (int kk = 0; kk < 2; ++kk)
      b[QN*2+nt][kk] = *(const bf16x8*)&Bs[BUF*16384 + row*64 + (((kk*4+lq) ^ (lr&7))*8)];
  }
}

template<int QM, int QN>
__device__ __forceinline__ void mmq(f32x4 (&acc)[8][4], const bf16x8 (&a)[4][2], const bf16x8 (&b)[4][2]){
  __builtin_amdgcn_s_setprio(1);
#pragma unroll
  for (int mt = 0; mt < 4; ++mt)
#pragma unroll
    for (int nt = 0; nt < 2; ++nt)
#pragma unroll
      for (int kk = 0; kk < 2; ++kk)
        acc[QM*4+mt][QN*2+nt] =
          __builtin_amdgcn_mfma_f32_16x16x32_bf16(a[mt][kk], b[QN*2+nt][kk], acc[QM*4+mt][QN*2+nt], 0, 0, 0);
  __builtin_amdgcn_s_setprio(0);
}

#define BAR __builtin_amdgcn_s_barrier()
#define WAITV4 asm volatile("s_waitcnt vmcnt(4)" ::: "memory")
#define WAITV0 asm volatile("s_waitcnt vmcnt(0)" ::: "memory")

// stage one 128-row half-tile: 8 waves x 2 gload_lds x 1KB = 16KB
#define STG_A(BUF,HALF,KT) do{ \
  async16(gA + (size_t)((HALF)*128    )*1024 + (size_t)(KT)*64, lA + (BUF)*16384 + (HALF)*8192      ); \
  async16(gA + (size_t)((HALF)*128 + 8)*1024 + (size_t)(KT)*64, lA + (BUF)*16384 + (HALF)*8192 + 512); }while(0)
#define STG_B(BUF,HALF,KT) do{ \
  async16(gB + (size_t)((HALF)*128    )*1024 + (size_t)(KT)*64, lB + (BUF)*16384 + (HALF)*8192      ); \
  async16(gB + (size_t)((HALF)*128 + 8)*1024 + (size_t)(KT)*64, lB + (BUF)*16384 + (HALF)*8192 + 512); }while(0)

__global__ __launch_bounds__(512,2) void k_gemm_big(
    const unsigned short* __restrict__ Abf,   // [25600][1024]
    const unsigned short* __restrict__ Btbf,  // [2048][1024]
    const float* __restrict__ q_e,
    const float* __restrict__ be_s,
    const float* __restrict__ bs_h, const float* __restrict__ ve,
    const float* __restrict__ vs1,  const float* __restrict__ vs2,
    float* __restrict__ et_raw, float* __restrict__ au_raw, float* __restrict__ et2_acc)
{
  __shared__ __align__(16) unsigned short As[2*16384];   // 2 bufs x 256x64
  __shared__ __align__(16) unsigned short Bs[2*16384];
  __shared__ float bias2_s[2][256];
  __shared__ float vv_s[256];
  __shared__ float rowW_s[256];
  __shared__ unsigned char rowSel_s[256];

  const int tid = threadIdx.x;
  // bijective chunked XCD swizzle (nwg = 800 = 8*100): each XCD gets consecutive bm panels
  const int lin = blockIdx.y*8 + blockIdx.x;
  const int lg  = (lin & 7)*100 + (lin >> 3);
  const int bn = lg & 7, bm = lg >> 3;

  const int r0  = bm*256;
  const int n0g = bn*256;
  const bool etmode = (n0g < 1024);
  const int dbase = etmode ? n0g : (n0g - 1024);
  const int b_lo = r0/400;
  const int b_hi = min(b_lo+1, 63);
  const bool bcross = (r0/400) != ((r0+255)/400);

  if (tid < 256){
    int r = r0 + tid;
    int bb = r/400;
    rowSel_s[tid] = (unsigned char)(bb - b_lo);
    rowW_s[tid]   = vs2[r - bb*400];
    vv_s[tid]     = etmode ? ve[dbase+tid] : vs1[dbase+tid];
    bias2_s[0][tid] = etmode ? (q_e[b_lo*1024 + dbase + tid] + be_s[dbase+tid]) : bs_h[dbase+tid];
    bias2_s[1][tid] = etmode ? (q_e[b_hi*1024 + dbase + tid] + be_s[dbase+tid]) : bs_h[dbase+tid];
  }

  const int lane = tid & 63, wid = tid >> 6;     // 8 waves
  const int wr = wid >> 2, wc = wid & 3;         // 2M x 4N wave grid
  const int lr = lane & 15, lq = lane >> 4;

  // staging addresses: wave w covers rows [w*16, w*16+16) of each half via 2 loads
  const int srow8 = lane >> 3;                   // 0..7
  const int csw   = (lane & 7) ^ srow8;          // inverse-swizzled global chunk
  const unsigned short* gA = Abf  + (size_t)(r0  + wid*16 + srow8)*1024 + csw*8;
  const unsigned short* gB = Btbf + (size_t)(n0g + wid*16 + srow8)*1024 + csw*8;
  unsigned short* lA = As + wid*1024;            // wave-uniform 1KB-segment base
  unsigned short* lB = Bs + wid*1024;

  f32x4 acc[8][4];
#pragma unroll
  for (int i = 0; i < 8; ++i)
#pragma unroll
    for (int j = 0; j < 4; ++j){ acc[i][j][0]=0.f; acc[i][j][1]=0.f; acc[i][j][2]=0.f; acc[i][j][3]=0.f; }

  bf16x8 a[4][2], b[4][2];

  // prologue: kt0 fully + kt1 B-halves (12 loads/wave); full drain also publishes shared init
  STG_B(0,0,0); STG_B(0,1,0);
  STG_A(0,0,0); STG_A(0,1,0);
  STG_B(1,0,1); STG_B(1,1,1);
  __syncthreads();

#pragma unroll 1
  for (int it = 0; it < 8; ++it){
    const int k1 = 2*it+1, k2 = 2*it+2, k3 = 2*it+3;
    const bool pf = (it < 7);
    // ---- K-tile 2it (buf0): quadrants (0,0) (0,1) (1,1) (1,0) ----
    // ph0
    ld_a<0,0>(As, a, wr, lr, lq); ld_b<0,0>(Bs, b, wc, lr, lq);
    STG_A(1,0,k1);
    BAR; mmq<0,0>(acc, a, b); BAR;
    // ph1
    ld_b<0,1>(Bs, b, wc, lr, lq);
    STG_A(1,1,k1);
    BAR; mmq<0,1>(acc, a, b); BAR;
    // ph2
    ld_a<0,1>(As, a, wr, lr, lq);
    if (pf) STG_B(0,0,k2);
    BAR; mmq<1,1>(acc, a, b); BAR;
    // ph3 (K-tile boundary: counted vmcnt BEFORE the barrier -> buf1 ready for all waves)
    if (pf) STG_B(0,1,k2);
    BAR; mmq<1,0>(acc, a, b);
    if (pf) { WAITV4; } else { WAITV0; }
    BAR;
    // ---- K-tile 2it+1 (buf1) ----
    // ph4
    ld_a<1,0>(As, a, wr, lr, lq); ld_b<1,0>(Bs, b, wc, lr, lq);
    if (pf) STG_A(0,0,k2);
    BAR; mmq<0,0>(acc, a, b); BAR;
    // ph5
    ld_b<1,1>(Bs, b, wc, lr, lq);
    if (pf) STG_A(0,1,k2);
    BAR; mmq<0,1>(acc, a, b); BAR;
    // ph6
    ld_a<1,1>(As, a, wr, lr, lq);
    if (pf) STG_B(1,0,k3);
    BAR; mmq<1,1>(acc, a, b); BAR;
    // ph7 (iteration boundary)
    if (pf) STG_B(1,1,k3);
    BAR; mmq<1,0>(acc, a, b);
    if (pf) { WAITV4; }
    BAR;
  }

  // ---- register epilogue ----
  float vvr[4], b0v[4], b1v[4];
#pragma unroll
  for (int nt = 0; nt < 4; ++nt){
    const int n = wc*64 + nt*16 + lr;
    vvr[nt] = vv_s[n];
    b0v[nt] = bias2_s[0][n];
    b1v[nt] = bias2_s[1][n];
  }

  float colacc0[4], colacc1[4];
#pragma unroll
  for (int nt = 0; nt < 4; ++nt){ colacc0[nt]=0.f; colacc1[nt]=0.f; }

  float* dst = etmode ? et_raw : au_raw;
#pragma unroll
  for (int mt = 0; mt < 8; ++mt){
#pragma unroll
    for (int v = 0; v < 4; ++v){
      const int m = wr*128 + mt*16 + lq*4 + v;
      const int sel = rowSel_s[m];
      const float rw = rowW_s[m];
      float rd = 0.f;
#pragma unroll
      for (int nt = 0; nt < 4; ++nt){
        float t = tanh_fast(acc[mt][nt][v] + (sel ? b1v[nt] : b0v[nt]));
        rd += t * vvr[nt];
        if (!etmode){
          float add = t * rw;
          colacc0[nt] += sel ? 0.f : add;
          colacc1[nt] += sel ? add : 0.f;
        }
      }
      rd += __shfl_xor(rd,1); rd += __shfl_xor(rd,2);
      rd += __shfl_xor(rd,4); rd += __shfl_xor(rd,8);
      if (lr == 0) atomicAdd(&dst[r0+m], rd);
    }
  }

  if (!etmode){
#pragma unroll
    for (int nt = 0; nt < 4; ++nt){
      float c0 = colacc0[nt]; c0 += __shfl_xor(c0,16); c0 += __shfl_xor(c0,32);
      float c1 = colacc1[nt]; c1 += __shfl_xor(c1,16); c1 += __shfl_xor(c1,32);
      if (lq == 0){
        const int n = wc*64 + nt*16 + lr;
        atomicAdd(&et2_acc[b_lo*1024 + dbase + n], c0);
        if (bcross) atomicAdd(&et2_acc[b_hi*1024 + dbase + n], c1);
      }
    }
  }
}

// ---------------- attention normalizations ----------------
__global__ __launch_bounds__(512) void k_attn_norm(const float* __restrict__ et_raw, const float* __restrict__ au_raw,
                                                   const float* __restrict__ et2_acc,
                                                   const float* __restrict__ sumts, const float* __restrict__ mask,
                                                   float* __restrict__ o_sumn, float* __restrict__ o_au,
                                                   float* __restrict__ o_et2, float* __restrict__ at_ws){
  int b = blockIdx.x, tid = threadIdx.x;
  __shared__ float red[512];
  float w = 0.f;
  if (tid < 400){
    float e  = __expf(et_raw[b*400+tid]);
    float st = sumts[b*400+tid];
    o_sumn[b*400+tid] = st + e;
    w = (e/st) * mask[b*400+tid];
  }
  red[tid] = w; __syncthreads();
  for (int s = 256; s > 0; s >>= 1){ if (tid < s) red[tid] += red[tid+s]; __syncthreads(); }
  float invw = 1.0f/red[0];
  __syncthreads();
  if (tid < 400) at_ws[b*400+tid] = w*invw;

  float a = 0.f;
  if (tid < 400) a = sigf(au_raw[b*400+tid]) * mask[b*400+tid];
  red[tid] = a; __syncthreads();
  for (int s = 256; s > 0; s >>= 1){ if (tid < s) red[tid] += red[tid+s]; __syncthreads(); }
  float inva = 1.0f/red[0];
  if (tid < 400) o_au[b*400+tid] = a*inva;

  for (int d = tid; d < 1024; d += 512) o_et2[b*1024+d] = sigf(et2_acc[b*1024+d]);
}

__global__ __launch_bounds__(256) void k_cte(const unsigned short* __restrict__ Abf, const float* __restrict__ at_ws,
                                             float* __restrict__ o_cte){
  int b = blockIdx.y;
  int d = blockIdx.x*256 + threadIdx.x;
  float acc = 0.f;
  for (int t = 0; t < 400; ++t)
    acc += at_ws[b*400+t] * bf2f(Abf[((size_t)(b*400+t))*1024 + d]);
  o_cte[b*1024+d] = acc;
}

// ---------------- intra-decoder attention ----------------
__global__ __launch_bounds__(256) void k_ed(const float* __restrict__ prev_s, const float* __restrict__ Wd_prev,
                                            const float* __restrict__ q_d, const float* __restrict__ bd_s,
                                            const float* __restrict__ vd, float* __restrict__ tmp_ed){
  int b = blockIdx.y;
  int j = (blockIdx.x & 1)*256 + threadIdx.x;
  int taub = (blockIdx.x >> 1)*25;
  float acc[25];
  #pragma unroll
  for (int t = 0; t < 25; ++t) acc[t] = 0.f;
  const float* ps = &prev_s[((size_t)b*50 + taub)*512];
  for (int k = 0; k < 512; ++k){
    float wv = Wd_prev[(size_t)k*512 + j];
    #pragma unroll
    for (int t = 0; t < 25; ++t) acc[t] += ps[(size_t)t*512 + k] * wv;
  }
  float qv = q_d[b*512+j] + bd_s[j], vdj = vd[j];
  #pragma unroll
  for (int t = 0; t < 25; ++t)
    tmp_ed[((size_t)b*50 + taub + t)*512 + j] = tanh_fast(acc[t] + qv) * vdj;
}

// ctd + p_gen fused (one block per b, 512 threads)
__global__ __launch_bounds__(512) void k_ctd_pgen(const float* __restrict__ tmp_ed, const float* __restrict__ prev_s,
                                                  const float* __restrict__ cte, const float* __restrict__ et2,
                                                  const float* __restrict__ h, const float* __restrict__ c,
                                                  const float* __restrict__ w_pg_cte, const float* __restrict__ w_pg_ctd,
                                                  const float* __restrict__ w_pg_st, const float* __restrict__ w_pg_em,
                                                  const float* __restrict__ b_pg_st,
                                                  float* __restrict__ ct_d, float* __restrict__ p_gen){
  int b = blockIdx.x, tid = threadIdx.x;
  __shared__ float ed_s[50];
  __shared__ float ad_s[50];
  __shared__ float red[512];
  if (tid < 400){
    int tau = tid >> 3, part = tid & 7;
    const float* tp = &tmp_ed[((size_t)b*50 + tau)*512 + part*64];
    float p = 0.f;
    for (int j = 0; j < 64; ++j) p += tp[j];
    p += __shfl_xor(p, 1); p += __shfl_xor(p, 2); p += __shfl_xor(p, 4);
    if (part == 0) ed_s[tau] = p;
  }
  __syncthreads();
  if (tid == 0){
    float mx = -1e30f;
    for (int t = 0; t < 50; ++t) mx = fmaxf(mx, ed_s[t]);
    float se = 0.f;
    for (int t = 0; t < 50; ++t){ float e = __expf(ed_s[t]-mx); ad_s[t] = e; se += e; }
    float inv = 1.f/se;
    for (int t = 0; t < 50; ++t) ad_s[t] *= inv;
  }
  __syncthreads();
  float acc = 0.f;
  for (int t = 0; t < 50; ++t) acc += ad_s[t]*prev_s[((size_t)b*50 + t)*512 + tid];
  ct_d[b*512+tid] = acc;

  // p_gen partials
  float s = acc*w_pg_ctd[tid] + h[b*512+tid]*w_pg_st[tid] + c[b*512+tid]*w_pg_st[512+tid];
  s += cte[b*1024+tid]*w_pg_cte[tid] + cte[b*1024+512+tid]*w_pg_cte[512+tid];
  s += et2[b*1024+tid]*w_pg_em[tid]  + et2[b*1024+512+tid]*w_pg_em[512+tid];
  red[tid] = s; __syncthreads();
  for (int k = 256; k > 0; k >>= 1){ if (tid < k) red[tid] += red[tid+k]; __syncthreads(); }
  if (tid == 0) p_gen[b] = sigf(red[0] + b_pg_st[0]);
}

// ---------------- logits MFMA with fused W_V1 transpose+convert ----------------
// logits[64][50000] = out_vec_bf[64][512] @ W_V1; B staged per-tile from fp32 [k][n]
// into padded LDS [n][k] (pitch 72 -> uniform bank spread).
__global__ __launch_bounds__(256,4) void k_logits_mfma(const unsigned short* __restrict__ Abf,  // [64][512] bf16
                                                       const float* __restrict__ W_V1,          // [512][50000] fp32
                                                       const float* __restrict__ b_V1, float* __restrict__ logits){
  __shared__ __align__(16) unsigned short As[64][72];
  __shared__ __align__(16) unsigned short Bs[64][72];
  const int tid = threadIdx.x;
  const int n0 = blockIdx.x*64;
  const int w = tid >> 6, lane = tid & 63;
  const int lr = lane & 15, lq = lane >> 4;

  const int am = tid >> 2, ac = tid & 3;        // A staging: m, chunk
  const int sn = tid & 63, skg = tid >> 6;      // B staging: n, k-group
  const int bnc = (n0 + sn < Vn) ? (n0 + sn) : (Vn - 1);

  f32x4 acc[4];
  #pragma unroll
  for (int i = 0; i < 4; ++i){ acc[i][0]=0.f; acc[i][1]=0.f; acc[i][2]=0.f; acc[i][3]=0.f; }

  for (int kt = 0; kt < 8; ++kt){
    const int k0 = kt*64;
    __syncthreads();
    // A tile: bf16, coalesced uint4 loads -> padded LDS
    #pragma unroll
    for (int s = 0; s < 2; ++s){
      uint4 av = *(const uint4*)&Abf[am*512 + k0 + (ac + 4*s)*8];
      *(uint4*)&As[am][(ac + 4*s)*8] = av;
    }
    // B tile: fp32 [k][n] -> bf16 LDS [n][k]
    #pragma unroll
    for (int jq = 0; jq < 4; ++jq){
      int kb = k0 + skg*16 + jq*4;
      float f0 = W_V1[(size_t)(kb+0)*Vn + bnc];
      float f1 = W_V1[(size_t)(kb+1)*Vn + bnc];
      float f2 = W_V1[(size_t)(kb+2)*Vn + bnc];
      float f3 = W_V1[(size_t)(kb+3)*Vn + bnc];
      ushort4 u; u.x = f2bf(f0); u.y = f2bf(f1); u.z = f2bf(f2); u.w = f2bf(f3);
      *(ushort4*)&Bs[sn][skg*16 + jq*4] = u;
    }
    __syncthreads();
    #pragma unroll
    for (int kk = 0; kk < 2; ++kk){
      bf16x8 a[4], b;
      #pragma unroll
      for (int i = 0; i < 4; ++i)
        a[i] = *(const bf16x8*)&As[i*16 + lr][kk*32 + lq*8];
      b = *(const bf16x8*)&Bs[w*16 + lr][kk*32 + lq*8];
      #pragma unroll
      for (int mt = 0; mt < 4; ++mt)
        acc[mt] = __builtin_amdgcn_mfma_f32_16x16x32_bf16(a[mt], b, acc[mt], 0, 0, 0);
    }
  }

  int n = n0 + w*16 + lr;
  if (n < Vn){
    float bb = b_V1[n];
    #pragma unroll
    for (int mt = 0; mt < 4; ++mt)
      #pragma unroll
      for (int v = 0; v < 4; ++v){
        int m = mt*16 + lq*4 + v;
        logits[(size_t)m*Vn + n] = acc[mt][v] + bb;
      }
  }
}

// softmax + pointer-scatter fused (block b owns row b)
__global__ __launch_bounds__(1024) void k_softmax_scatter(const float* __restrict__ logits, const float* __restrict__ p_gen,
                                                          const int* __restrict__ ebev, const float* __restrict__ at_ws,
                                                          float* __restrict__ final_out){
  int b = blockIdx.x, tid = threadIdx.x;
  __shared__ float red[1024];
  const float* lrow = &logits[(size_t)b*Vn];
  float mx = -1e30f;
  for (int v = tid; v < Vn; v += 1024) mx = fmaxf(mx, lrow[v]);
  red[tid] = mx; __syncthreads();
  for (int s = 512; s > 0; s >>= 1){ if (tid < s) red[tid] = fmaxf(red[tid], red[tid+s]); __syncthreads(); }
  mx = red[0]; __syncthreads();
  float se = 0.f;
  for (int v = tid; v < Vn; v += 1024) se += __expf(lrow[v]-mx);
  red[tid] = se; __syncthreads();
  for (int s = 512; s > 0; s >>= 1){ if (tid < s) red[tid] += red[tid+s]; __syncthreads(); }
  float pgb = p_gen[b];
  float scale = pgb/red[0];
  float* frow = &final_out[(size_t)b*VEXTn];
  for (int v = tid; v < Vn; v += 1024) frow[v] = __expf(lrow[v]-mx)*scale;
  for (int v = Vn+tid; v < VEXTn; v += 1024) frow[v] = 0.f;
  __syncthreads();
  if (tid < 400){
    float add = (1.f - pgb) * at_ws[b*400+tid];
    atomicAdd(&frow[ebev[b*400+tid]], add);
  }
}

__global__ __launch_bounds__(256) void k_prevs(const float* __restrict__ prev_s, const float* __restrict__ h,
                                               float* __restrict__ o_prevs){
  int i = blockIdx.x*256 + threadIdx.x;
  int b = i / (51*512);
  int rem = i - b*51*512;
  int tau = rem >> 9, j = rem & 511;
  o_prevs[i] = (tau < 50) ? prev_s[((size_t)b*50 + tau)*512 + j] : h[b*512+j];
}

extern "C" void kernel_launch(void* const* d_in, const int* in_sizes, int n_in,
                              void* d_out, int out_size, void* d_ws, size_t ws_size,
                              hipStream_t stream)
{
  const float* x_t    = (const float*)d_in[0];
  const float* s_h    = (const float*)d_in[1];
  const float* s_c    = (const float*)d_in[2];
  const float* enc    = (const float*)d_in[3];
  const float* mask   = (const float*)d_in[4];
  const float* ct_e   = (const float*)d_in[5];
  const float* sumts  = (const float*)d_in[7];
  const float* prev_s = (const float*)d_in[8];
  const int*   ebev   = (const int*)d_in[9];
  const float* W_xc   = (const float*)d_in[10];
  const float* b_xc   = (const float*)d_in[11];
  const float* W_ih   = (const float*)d_in[12];
  const float* W_hh   = (const float*)d_in[13];
  const float* b_ih   = (const float*)d_in[14];
  const float* b_hh   = (const float*)d_in[15];
  const float* We_h   = (const float*)d_in[16];
  const float* We_s   = (const float*)d_in[17];
  const float* be_s   = (const float*)d_in[18];
  const float* ve     = (const float*)d_in[19];
  const float* Ws_h   = (const float*)d_in[20];
  const float* bs_h   = (const float*)d_in[21];
  const float* vs1    = (const float*)d_in[22];
  const float* vs2    = (const float*)d_in[23];
  const float* Wd_prev= (const float*)d_in[24];
  const float* Wd_s   = (const float*)d_in[25];
  const float* bd_s   = (const float*)d_in[26];
  const float* vd     = (const float*)d_in[27];
  const float* w_pg_em  = (const float*)d_in[28];
  const float* w_pg_cte = (const float*)d_in[29];
  const float* w_pg_ctd = (const float*)d_in[30];
  const float* w_pg_st  = (const float*)d_in[31];
  const float* b_pg_st  = (const float*)d_in[32];
  const float* W_V    = (const float*)d_in[33];
  const float* b_V    = (const float*)d_in[34];
  const float* W_V1   = (const float*)d_in[35];
  const float* b_V1   = (const float*)d_in[36];
  (void)in_sizes; (void)n_in; (void)out_size; (void)ws_size;

  float* out = (float*)d_out;
  float* o_final = out;
  float* o_h     = out + 3206400;
  float* o_c     = out + 3239168;
  float* o_cte   = out + 3271936;
  float* o_au    = out + 3337472;
  float* o_et2   = out + 3363072;
  float* o_sumn  = out + 3428608;
  float* o_prevs = out + 3454208;

  char* ws = (char*)d_ws;
  // zeroed accumulators
  float* et_raw    = (float*)(ws + 0);
  float* au_raw    = (float*)(ws + 102400);
  float* et2_acc   = (float*)(ws + 204800);
  float* x_acc     = (float*)(ws + 466944);
  float* gates_acc = (float*)(ws + 532480);
  float* qe_acc    = (float*)(ws + 1056768);
  float* qd_acc    = (float*)(ws + 1318912);
  float* ov_acc    = (float*)(ws + 1449984);    // end 1581056
  // scratch
  float* at_ws   = (float*)(ws + 1581056);
  float* ct_d    = (float*)(ws + 1683456);
  float* p_gen   = (float*)(ws + 1814528);
  float* tmp_ed  = (float*)(ws + 1900544);      // 6.55 MB (shares region with logits)
  float* logits  = (float*)(ws + 1900544);      // 12.8 MB -> end 14700544
  unsigned short* out_vec_bf = (unsigned short*)(ws + 14700544);
  unsigned short* enc_bf  = (unsigned short*)(ws + 14780416);   // 52.4 MB
  unsigned short* Bt_bf   = (unsigned short*)(ws + 67209216);   // 4 MB

  hipMemsetAsync(ws, 0, 1581056, stream);
  k_conv_enc<<<25600, 256, 0, stream>>>(enc, enc_bf);
  k_transpose<<<dim3(32,32,2), 256, 0, stream>>>(We_h, Ws_h, Bt_bf);
  k_gemv_x<<<dim3(1,64,5), 256, 0, stream>>>(x_t, ct_e, W_xc, x_acc);
  k_gemv_gates<<<dim3(8,64,3), 256, 0, stream>>>(x_acc, b_xc, s_h, W_ih, W_hh, gates_acc);
  k_lstm_act<<<dim3(2,64), 256, 0, stream>>>(gates_acc, b_ih, b_hh, s_c, o_h, o_c);
  k_gemv_qe<<<dim3(4,64,4), 256, 0, stream>>>(o_h, o_c, We_s, qe_acc);
  k_gemv_qd<<<dim3(2,64,2), 256, 0, stream>>>(o_h, Wd_s, qd_acc);
  k_gemm_big<<<dim3(8,100), 512, 0, stream>>>(enc_bf, Bt_bf, qe_acc, be_s, bs_h, ve, vs1, vs2,
                                              et_raw, au_raw, et2_acc);
  k_attn_norm<<<64, 512, 0, stream>>>(et_raw, au_raw, et2_acc, sumts, mask, o_sumn, o_au, o_et2, at_ws);
  k_cte<<<dim3(4,64), 256, 0, stream>>>(enc_bf, at_ws, o_cte);
  k_ed<<<dim3(4,64), 256, 0, stream>>>(prev_s, Wd_prev, qd_acc, bd_s, vd, tmp_ed);
  k_ctd_pgen<<<64, 512, 0, stream>>>(tmp_ed, prev_s, o_cte, o_et2, o_h, o_c,
                                     w_pg_cte, w_pg_ctd, w_pg_st, w_pg_em, b_pg_st, ct_d, p_gen);
  k_gemv_outvec<<<dim3(2,64,6), 256, 0, stream>>>(o_h, o_cte, ct_d, o_et2, W_V, ov_acc);
  k_outvec_fin<<<128, 256, 0, stream>>>(ov_acc, b_V, out_vec_bf);
  k_logits_mfma<<<782, 256, 0, stream>>>(out_vec_bf, W_V1, b_V1, logits);
  k_softmax_scatter<<<64, 1024, 0, stream>>>(logits, p_gen, ebev, at_ws, o_final);
  k_prevs<<<6528, 256, 0, stream>>>(prev_s, o_h, o_prevs);
}

// Round 2
// 870.996 us; speedup vs baseline: 1.0501x; 1.0501x over previous
//
#include <hip/hip_runtime.h>
#include <stdint.h>

#define Bn 64
#define Tn 400
#define Hn 512
#define En 256
#define Vn 50000
#define NOOVn 100
#define TPn 50
#define H2n 1024
#define VEXTn (Vn+NOOVn)  // 50100

typedef __bf16 bf16x8 __attribute__((ext_vector_type(8)));
typedef float  f32x4  __attribute__((ext_vector_type(4)));

__device__ __forceinline__ float sigf(float x){ return 1.0f/(1.0f+__expf(-x)); }
__device__ __forceinline__ float tanh_fast(float x){
  float e = __expf(2.0f*x);
  return (e-1.0f)/(e+1.0f);
}

__device__ __forceinline__ unsigned short f2bf(float f){
  union { float f; uint32_t u; } v; v.f = f;
  uint32_t r = v.u + 0x7FFFu + ((v.u >> 16) & 1u);
  return (unsigned short)(r >> 16);
}
__device__ __forceinline__ float bf2f(unsigned short s){
  union { uint32_t u; float f; } v; v.u = ((uint32_t)s) << 16;
  return v.f;
}

__device__ __forceinline__ void async16(const void* g, void* l){
  __builtin_amdgcn_global_load_lds((__attribute__((address_space(1))) void*)g,
                                   (__attribute__((address_space(3))) void*)l, 16, 0, 0);
}

// ---------------- conversions ----------------
__global__ __launch_bounds__(256) void k_conv_enc(const float* __restrict__ enc, unsigned short* __restrict__ out){
  int i = blockIdx.x*256 + threadIdx.x;
  const float4* e4 = (const float4*)enc;
  float4 v = e4[i];
  ushort4 r;
  r.x = f2bf(v.x); r.y = f2bf(v.y); r.z = f2bf(v.z); r.w = f2bf(v.w);
  ((ushort4*)out)[i] = r;
}

// Bt[n][k] = W[k][n], n<1024 from W1 (We_h), n>=1024 from W2 (Ws_h)
__global__ __launch_bounds__(256) void k_transpose(const float* __restrict__ W1, const float* __restrict__ W2,
                                                   unsigned short* __restrict__ Bt){
  const float* W = blockIdx.z ? W2 : W1;
  int nbase = blockIdx.z * 1024;
  __shared__ float tile[32][33];
  int k0 = blockIdx.y*32, n0 = blockIdx.x*32;
  int tx = threadIdx.x & 31, ty = threadIdx.x >> 5;  // ty 0..7
  for (int i = 0; i < 32; i += 8)
    tile[ty+i][tx] = W[(size_t)(k0+ty+i)*1024 + n0+tx];
  __syncthreads();
  for (int i = 0; i < 32; i += 8)
    Bt[(size_t)(nbase+n0+ty+i)*1024 + k0+tx] = f2bf(tile[tx][ty+i]);
}

// ---------------- split-K GEMV chain (M=64, fp32 atomics) ----------------
__global__ __launch_bounds__(256) void k_gemv_x(const float* __restrict__ x_t, const float* __restrict__ ct_e,
                                                const float* __restrict__ W_xc, float* __restrict__ x_acc){
  int n = threadIdx.x;
  int b = blockIdx.y;
  int k0 = blockIdx.z*256;        // z 0..4 (K=1280)
  float acc = 0.f;
  #pragma unroll 4
  for (int kk = 0; kk < 256; ++kk){
    int k = k0 + kk;
    float a = (k < 256) ? x_t[b*256+k] : ct_e[b*1024 + k - 256];
    acc += a * W_xc[(size_t)k*256 + n];
  }
  atomicAdd(&x_acc[b*256+n], acc);
}

__global__ __launch_bounds__(256) void k_gemv_gates(const float* __restrict__ x_acc, const float* __restrict__ b_xc,
                                                    const float* __restrict__ s_h,
                                                    const float* __restrict__ W_ih, const float* __restrict__ W_hh,
                                                    float* __restrict__ gates_acc){
  int n = blockIdx.x*256 + threadIdx.x;  // 0..2047
  int b = blockIdx.y;
  int k0 = blockIdx.z*256;               // z 0..2 (K=768)
  float acc = 0.f;
  #pragma unroll 4
  for (int kk = 0; kk < 256; ++kk){
    int k = k0 + kk;
    float a; const float* wrow;
    if (k < 256){ a = x_acc[b*256+k] + b_xc[k]; wrow = &W_ih[(size_t)k*2048]; }
    else        { a = s_h[b*512 + k-256];       wrow = &W_hh[(size_t)(k-256)*2048]; }
    acc += a * wrow[n];
  }
  atomicAdd(&gates_acc[(size_t)b*2048 + n], acc);
}

__global__ __launch_bounds__(256) void k_lstm_act(const float* __restrict__ gates_acc,
                                                  const float* __restrict__ b_ih, const float* __restrict__ b_hh,
                                                  const float* __restrict__ s_c,
                                                  float* __restrict__ h_out, float* __restrict__ c_out){
  int b = blockIdx.y;
  int j = blockIdx.x*256 + threadIdx.x;
  const float* g = &gates_acc[(size_t)b*2048];
  float gi = g[j]      + b_ih[j]      + b_hh[j];
  float gf = g[512+j]  + b_ih[512+j]  + b_hh[512+j];
  float gg = g[1024+j] + b_ih[1024+j] + b_hh[1024+j];
  float go = g[1536+j] + b_ih[1536+j] + b_hh[1536+j];
  float c = sigf(gf)*s_c[b*512+j] + sigf(gi)*tanh_fast(gg);
  float h = sigf(go)*tanh_fast(c);
  h_out[b*512+j] = h;
  c_out[b*512+j] = c;
}

__global__ __launch_bounds__(256) void k_gemv_qe(const float* __restrict__ h, const float* __restrict__ c,
                                                 const float* __restrict__ We_s, float* __restrict__ qe_acc){
  int n = blockIdx.x*256 + threadIdx.x;
  int b = blockIdx.y;
  int k0 = blockIdx.z*256;
  float acc = 0.f;
  #pragma unroll 4
  for (int kk = 0; kk < 256; ++kk){
    int k = k0 + kk;
    float a = (k < 512) ? h[b*512+k] : c[b*512 + k-512];
    acc += a * We_s[(size_t)k*1024 + n];
  }
  atomicAdd(&qe_acc[b*1024+n], acc);
}

__global__ __launch_bounds__(256) void k_gemv_qd(const float* __restrict__ h, const float* __restrict__ Wd_s,
                                                 float* __restrict__ qd_acc){
  int n = blockIdx.x*256 + threadIdx.x;
  int b = blockIdx.y;
  int k0 = blockIdx.z*256;
  float acc = 0.f;
  #pragma unroll 4
  for (int kk = 0; kk < 256; ++kk){
    int k = k0 + kk;
    acc += h[b*512+k] * Wd_s[(size_t)k*512 + n];
  }
  atomicAdd(&qd_acc[b*512+n], acc);
}

__global__ __launch_bounds__(256) void k_gemv_outvec(const float* __restrict__ h, const float* __restrict__ cte,
                                                     const float* __restrict__ ctd, const float* __restrict__ et2,
                                                     const float* __restrict__ W_V, float* __restrict__ ov_acc){
  int n = blockIdx.x*256 + threadIdx.x;
  int b = blockIdx.y;
  int z = blockIdx.z;
  const float* base;
  switch(z){
    case 0:  base = &h[b*512];        break;
    case 1:  base = &cte[b*1024];     break;
    case 2:  base = &cte[b*1024+512]; break;
    case 3:  base = &ctd[b*512];      break;
    case 4:  base = &et2[b*1024];     break;
    default: base = &et2[b*1024+512]; break;
  }
  const float* wrow = &W_V[(size_t)z*512*512];
  float acc = 0.f;
  #pragma unroll 4
  for (int kk = 0; kk < 512; ++kk)
    acc += base[kk] * wrow[(size_t)kk*512 + n];
  atomicAdd(&ov_acc[b*512+n], acc);
}

__global__ __launch_bounds__(256) void k_outvec_fin(const float* __restrict__ ov_acc, const float* __restrict__ b_V,
                                                    unsigned short* __restrict__ out_vec_bf){
  int i = blockIdx.x*256 + threadIdx.x;
  int j = i & 511;
  out_vec_bf[i] = f2bf(ov_acc[i] + b_V[j]);
}

// ---------------- the big fused dual-GEMM (m97 pattern + XOR-swizzled LDS) ----------------
// REVERTED to the 128^2 / 256-thread / 4-blocks-per-CU version (150 us measured).
// The 256^2 8-phase port regressed (175 us): 132KB LDS -> 1 block/CU killed the
// cross-block overlap that hides barrier drains, and K=1024 is too short (8 iters)
// to amortize the deep pipeline.
__global__ __launch_bounds__(256,4) void k_gemm_big(
    const unsigned short* __restrict__ Abf,   // [25600][1024]
    const unsigned short* __restrict__ Btbf,  // [2048][1024]
    const float* __restrict__ q_e,
    const float* __restrict__ be_s,
    const float* __restrict__ bs_h, const float* __restrict__ ve,
    const float* __restrict__ vs1,  const float* __restrict__ vs2,
    float* __restrict__ et_raw, float* __restrict__ au_raw, float* __restrict__ et2_acc)
{
  __shared__ __align__(16) unsigned short As[128*64];
  __shared__ __align__(16) unsigned short Bs[128*64];
  __shared__ float bias2_s[2][128];
  __shared__ float vv_s[128];
  __shared__ float rowW_s[128];
  __shared__ unsigned char rowSel_s[128];

  const int tid = threadIdx.x;
  const int bn = blockIdx.x, bm = blockIdx.y;
  const int r0  = bm*128;
  const int n0g = bn*128;
  const bool etmode = (n0g < 1024);
  const int dbase = etmode ? n0g : (n0g - 1024);
  const int b_lo = r0/400;
  const int b_hi = min(b_lo+1, 63);
  const bool bcross = (r0/400) != ((r0+127)/400);

  if (tid < 128){
    int r = r0 + tid;
    int bb = r/400;
    rowSel_s[tid] = (unsigned char)(bb - b_lo);
    rowW_s[tid]   = vs2[r - bb*400];
    vv_s[tid]     = etmode ? ve[dbase+tid] : vs1[dbase+tid];
    bias2_s[0][tid] = etmode ? (q_e[b_lo*1024 + dbase + tid] + be_s[dbase+tid]) : bs_h[dbase+tid];
    bias2_s[1][tid] = etmode ? (q_e[b_hi*1024 + dbase + tid] + be_s[dbase+tid]) : bs_h[dbase+tid];
  }

  const int w = tid >> 6, lane = tid & 63;
  const int wm = w & 1, wn = w >> 1;
  const int lr = lane & 15, lq = lane >> 4;

  // XOR-swizzled staging: LDS slot (row, j) holds global chunk j ^ (row&7)
  const int srow = lane >> 3;
  const int c_g  = (lane & 7) ^ (srow & 7);      // swizzled global chunk for this lane
  const unsigned short* gA0 = Abf  + (size_t)(r0  + w*32 + srow)*1024 + c_g*8;
  const unsigned short* gB0 = Btbf + (size_t)(n0g + w*32 + srow)*1024 + c_g*8;
  unsigned short* lA0 = As + w*32*64;
  unsigned short* lB0 = Bs + w*32*64;

  f32x4 acc[4][4];
  #pragma unroll
  for (int i = 0; i < 4; ++i)
    #pragma unroll
    for (int j = 0; j < 4; ++j){ acc[i][j][0]=0.f; acc[i][j][1]=0.f; acc[i][j][2]=0.f; acc[i][j][3]=0.f; }

  for (int kt = 0; kt < 16; ++kt){
    __syncthreads();
    #pragma unroll
    for (int q = 0; q < 4; ++q){
      async16(gA0 + (size_t)q*8*1024 + kt*64, lA0 + q*512);
      async16(gB0 + (size_t)q*8*1024 + kt*64, lB0 + q*512);
    }
    __syncthreads();
    #pragma unroll
    for (int kk = 0; kk < 2; ++kk){
      const int slot8 = ((kk*4 + lq) ^ (lr & 7)) * 8;   // de-swizzled read
      bf16x8 a[4], b[4];
      #pragma unroll
      for (int i = 0; i < 4; ++i){
        a[i] = *(const bf16x8*)&As[(wm*64 + i*16 + lr)*64 + slot8];
        b[i] = *(const bf16x8*)&Bs[(wn*64 + i*16 + lr)*64 + slot8];
      }
      #pragma unroll
      for (int mt = 0; mt < 4; ++mt)
        #pragma unroll
        for (int nt = 0; nt < 4; ++nt)
          acc[mt][nt] = __builtin_amdgcn_mfma_f32_16x16x32_bf16(a[mt], b[nt], acc[mt][nt], 0, 0, 0);
    }
  }

  // ---- register epilogue ----
  float vvr[4], bias0[4], bias1[4];
  #pragma unroll
  for (int nt = 0; nt < 4; ++nt){
    int n = wn*64 + nt*16 + lr;
    vvr[nt]   = vv_s[n];
    bias0[nt] = bias2_s[0][n];
    bias1[nt] = bias2_s[1][n];
  }

  float rowdot[16];
  float colacc[4][2];
  #pragma unroll
  for (int nt = 0; nt < 4; ++nt){ colacc[nt][0]=0.f; colacc[nt][1]=0.f; }

  #pragma unroll
  for (int mt = 0; mt < 4; ++mt){
    #pragma unroll
    for (int v = 0; v < 4; ++v){
      int m = wm*64 + mt*16 + lq*4 + v;
      int sel = rowSel_s[m];
      float rw = rowW_s[m];
      float rd = 0.f;
      #pragma unroll
      for (int nt = 0; nt < 4; ++nt){
        float t = tanh_fast(acc[mt][nt][v] + (sel ? bias1[nt] : bias0[nt]));
        rd += t * vvr[nt];
        if (!etmode) colacc[nt][sel] += t * rw;
      }
      rowdot[mt*4+v] = rd;
    }
  }

  #pragma unroll
  for (int i = 0; i < 16; ++i){
    float s = rowdot[i];
    s += __shfl_xor(s,1); s += __shfl_xor(s,2); s += __shfl_xor(s,4); s += __shfl_xor(s,8);
    rowdot[i] = s;
  }
  if (lr == 0){
    float* dst = etmode ? et_raw : au_raw;
    #pragma unroll
    for (int i = 0; i < 16; ++i){
      int m = wm*64 + (i>>2)*16 + lq*4 + (i&3);
      atomicAdd(&dst[r0+m], rowdot[i]);
    }
  }

  if (!etmode){
    #pragma unroll
    for (int nt = 0; nt < 4; ++nt){
      #pragma unroll
      for (int s = 0; s < 2; ++s){
        float c = colacc[nt][s];
        c += __shfl_xor(c,16); c += __shfl_xor(c,32);
        if (lq == 0 && (s == 0 || bcross)){
          int n = wn*64 + nt*16 + lr;
          atomicAdd(&et2_acc[(b_lo+s)*1024 + dbase + n], c);
        }
      }
    }
  }
}

// ---------------- attention normalizations ----------------
__global__ __launch_bounds__(512) void k_attn_norm(const float* __restrict__ et_raw, const float* __restrict__ au_raw,
                                                   const float* __restrict__ et2_acc,
                                                   const float* __restrict__ sumts, const float* __restrict__ mask,
                                                   float* __restrict__ o_sumn, float* __restrict__ o_au,
                                                   float* __restrict__ o_et2, float* __restrict__ at_ws){
  int b = blockIdx.x, tid = threadIdx.x;
  __shared__ float red[512];
  float w = 0.f;
  if (tid < 400){
    float e  = __expf(et_raw[b*400+tid]);
    float st = sumts[b*400+tid];
    o_sumn[b*400+tid] = st + e;
    w = (e/st) * mask[b*400+tid];
  }
  red[tid] = w; __syncthreads();
  for (int s = 256; s > 0; s >>= 1){ if (tid < s) red[tid] += red[tid+s]; __syncthreads(); }
  float invw = 1.0f/red[0];
  __syncthreads();
  if (tid < 400) at_ws[b*400+tid] = w*invw;

  float a = 0.f;
  if (tid < 400) a = sigf(au_raw[b*400+tid]) * mask[b*400+tid];
  red[tid] = a; __syncthreads();
  for (int s = 256; s > 0; s >>= 1){ if (tid < s) red[tid] += red[tid+s]; __syncthreads(); }
  float inva = 1.0f/red[0];
  if (tid < 400) o_au[b*400+tid] = a*inva;

  for (int d = tid; d < 1024; d += 512) o_et2[b*1024+d] = sigf(et2_acc[b*1024+d]);
}

// vectorized: 2 bf16 per lane per t-step (uint load)
__global__ __launch_bounds__(256) void k_cte(const unsigned short* __restrict__ Abf, const float* __restrict__ at_ws,
                                             float* __restrict__ o_cte){
  int b = blockIdx.y;
  int d0 = (blockIdx.x*256 + threadIdx.x)*2;
  float a0 = 0.f, a1 = 0.f;
  for (int t = 0; t < 400; ++t){
    float w = at_ws[b*400+t];
    uint32_t v = *(const uint32_t*)&Abf[((size_t)(b*400+t))*1024 + d0];
    a0 += w * bf2f((unsigned short)(v & 0xffffu));
    a1 += w * bf2f((unsigned short)(v >> 16));
  }
  float2 r; r.x = a0; r.y = a1;
  *(float2*)&o_cte[b*1024 + d0] = r;
}

// ---------------- intra-decoder attention ----------------
__global__ __launch_bounds__(256) void k_ed(const float* __restrict__ prev_s, const float* __restrict__ Wd_prev,
                                            const float* __restrict__ q_d, const float* __restrict__ bd_s,
                                            const float* __restrict__ vd, float* __restrict__ tmp_ed){
  int b = blockIdx.y;
  int j = (blockIdx.x & 1)*256 + threadIdx.x;
  int taub = (blockIdx.x >> 1)*25;
  float acc[25];
  #pragma unroll
  for (int t = 0; t < 25; ++t) acc[t] = 0.f;
  const float* ps = &prev_s[((size_t)b*50 + taub)*512];
  for (int k = 0; k < 512; ++k){
    float wv = Wd_prev[(size_t)k*512 + j];
    #pragma unroll
    for (int t = 0; t < 25; ++t) acc[t] += ps[(size_t)t*512 + k] * wv;
  }
  float qv = q_d[b*512+j] + bd_s[j], vdj = vd[j];
  #pragma unroll
  for (int t = 0; t < 25; ++t)
    tmp_ed[((size_t)b*50 + taub + t)*512 + j] = tanh_fast(acc[t] + qv) * vdj;
}

// ctd + p_gen fused (one block per b, 512 threads)
__global__ __launch_bounds__(512) void k_ctd_pgen(const float* __restrict__ tmp_ed, const float* __restrict__ prev_s,
                                                  const float* __restrict__ cte, const float* __restrict__ et2,
                                                  const float* __restrict__ h, const float* __restrict__ c,
                                                  const float* __restrict__ w_pg_cte, const float* __restrict__ w_pg_ctd,
                                                  const float* __restrict__ w_pg_st, const float* __restrict__ w_pg_em,
                                                  const float* __restrict__ b_pg_st,
                                                  float* __restrict__ ct_d, float* __restrict__ p_gen){
  int b = blockIdx.x, tid = threadIdx.x;
  __shared__ float ed_s[50];
  __shared__ float ad_s[50];
  __shared__ float red[512];
  if (tid < 400){
    int tau = tid >> 3, part = tid & 7;
    const float* tp = &tmp_ed[((size_t)b*50 + tau)*512 + part*64];
    float p = 0.f;
    for (int j = 0; j < 64; ++j) p += tp[j];
    p += __shfl_xor(p, 1); p += __shfl_xor(p, 2); p += __shfl_xor(p, 4);
    if (part == 0) ed_s[tau] = p;
  }
  __syncthreads();
  if (tid == 0){
    float mx = -1e30f;
    for (int t = 0; t < 50; ++t) mx = fmaxf(mx, ed_s[t]);
    float se = 0.f;
    for (int t = 0; t < 50; ++t){ float e = __expf(ed_s[t]-mx); ad_s[t] = e; se += e; }
    float inv = 1.f/se;
    for (int t = 0; t < 50; ++t) ad_s[t] *= inv;
  }
  __syncthreads();
  float acc = 0.f;
  for (int t = 0; t < 50; ++t) acc += ad_s[t]*prev_s[((size_t)b*50 + t)*512 + tid];
  ct_d[b*512+tid] = acc;

  // p_gen partials
  float s = acc*w_pg_ctd[tid] + h[b*512+tid]*w_pg_st[tid] + c[b*512+tid]*w_pg_st[512+tid];
  s += cte[b*1024+tid]*w_pg_cte[tid] + cte[b*1024+512+tid]*w_pg_cte[512+tid];
  s += et2[b*1024+tid]*w_pg_em[tid]  + et2[b*1024+512+tid]*w_pg_em[512+tid];
  red[tid] = s; __syncthreads();
  for (int k = 256; k > 0; k >>= 1){ if (tid < k) red[tid] += red[tid+k]; __syncthreads(); }
  if (tid == 0) p_gen[b] = sigf(red[0] + b_pg_st[0]);
}

// ---------------- logits MFMA with fused W_V1 transpose+convert AND softmax partials ----------------
// logits[64][50000] = out_vec_bf[64][512] @ W_V1. Epilogue additionally reduces each
// block's 64-column slice to per-row (max, sum-of-exp) partials -> removes one full
// 12.8MB logits pass and the 64-block softmax bottleneck.
__global__ __launch_bounds__(256,4) void k_logits_mfma(const unsigned short* __restrict__ Abf,  // [64][512] bf16
                                                       const float* __restrict__ W_V1,          // [512][50000] fp32
                                                       const float* __restrict__ b_V1, float* __restrict__ logits,
                                                       float* __restrict__ mpart, float* __restrict__ spart){
  __shared__ __align__(16) unsigned short As[64][72];
  __shared__ __align__(16) unsigned short Bs[64][72];
  __shared__ float pred[4][64];
  __shared__ float gmax[64];
  const int tid = threadIdx.x;
  const int n0 = blockIdx.x*64;
  const int w = tid >> 6, lane = tid & 63;
  const int lr = lane & 15, lq = lane >> 4;

  const int am = tid >> 2, ac = tid & 3;        // A staging: m, chunk
  const int sn = tid & 63, skg = tid >> 6;      // B staging: n, k-group
  const int bnc = (n0 + sn < Vn) ? (n0 + sn) : (Vn - 1);

  f32x4 acc[4];
  #pragma unroll
  for (int i = 0; i < 4; ++i){ acc[i][0]=0.f; acc[i][1]=0.f; acc[i][2]=0.f; acc[i][3]=0.f; }

  for (int kt = 0; kt < 8; ++kt){
    const int k0 = kt*64;
    __syncthreads();
    // A tile: bf16, coalesced uint4 loads -> padded LDS
    #pragma unroll
    for (int s = 0; s < 2; ++s){
      uint4 av = *(const uint4*)&Abf[am*512 + k0 + (ac + 4*s)*8];
      *(uint4*)&As[am][(ac + 4*s)*8] = av;
    }
    // B tile: fp32 [k][n] -> bf16 LDS [n][k]
    #pragma unroll
    for (int jq = 0; jq < 4; ++jq){
      int kb = k0 + skg*16 + jq*4;
      float f0 = W_V1[(size_t)(kb+0)*Vn + bnc];
      float f1 = W_V1[(size_t)(kb+1)*Vn + bnc];
      float f2 = W_V1[(size_t)(kb+2)*Vn + bnc];
      float f3 = W_V1[(size_t)(kb+3)*Vn + bnc];
      ushort4 u; u.x = f2bf(f0); u.y = f2bf(f1); u.z = f2bf(f2); u.w = f2bf(f3);
      *(ushort4*)&Bs[sn][skg*16 + jq*4] = u;
    }
    __syncthreads();
    #pragma unroll
    for (int kk = 0; kk < 2; ++kk){
      bf16x8 a[4], b;
      #pragma unroll
      for (int i = 0; i < 4; ++i)
        a[i] = *(const bf16x8*)&As[i*16 + lr][kk*32 + lq*8];
      b = *(const bf16x8*)&Bs[w*16 + lr][kk*32 + lq*8];
      #pragma unroll
      for (int mt = 0; mt < 4; ++mt)
        acc[mt] = __builtin_amdgcn_mfma_f32_16x16x32_bf16(a[mt], b, acc[mt], 0, 0, 0);
    }
  }

  const int n = n0 + w*16 + lr;
  const bool nok = (n < Vn);
  const float bb = nok ? b_V1[n] : 0.f;

  // store logits + per-row column-max partial (butterfly over lr = cols)
  #pragma unroll
  for (int mt = 0; mt < 4; ++mt)
    #pragma unroll
    for (int v = 0; v < 4; ++v){
      int m = mt*16 + lq*4 + v;
      float val = nok ? (acc[mt][v] + bb) : -1e30f;
      if (nok) logits[(size_t)m*Vn + n] = val;
      float t = val;
      t = fmaxf(t, __shfl_xor(t,1)); t = fmaxf(t, __shfl_xor(t,2));
      t = fmaxf(t, __shfl_xor(t,4)); t = fmaxf(t, __shfl_xor(t,8));
      if (lr == 0) pred[w][m] = t;
    }
  __syncthreads();
  if (tid < 64)
    gmax[tid] = fmaxf(fmaxf(pred[0][tid], pred[1][tid]), fmaxf(pred[2][tid], pred[3][tid]));
  __syncthreads();

  // per-row sum-of-exp partial
  #pragma unroll
  for (int mt = 0; mt < 4; ++mt)
    #pragma unroll
    for (int v = 0; v < 4; ++v){
      int m = mt*16 + lq*4 + v;
      float e = nok ? __expf(acc[mt][v] + bb - gmax[m]) : 0.f;
      e += __shfl_xor(e,1); e += __shfl_xor(e,2);
      e += __shfl_xor(e,4); e += __shfl_xor(e,8);
      if (lr == 0) pred[w][m] = e;
    }
  __syncthreads();
  if (tid < 64){
    float s = pred[0][tid] + pred[1][tid] + pred[2][tid] + pred[3][tid];
    mpart[(size_t)tid*782 + blockIdx.x] = gmax[tid];
    spart[(size_t)tid*782 + blockIdx.x] = s;
  }
}

// combine 782 per-block partials per row, write final probs for a 6250-col slice
__global__ __launch_bounds__(1024) void k_softmax_write(const float* __restrict__ logits,
                                                        const float* __restrict__ mpart, const float* __restrict__ spart,
                                                        const float* __restrict__ p_gen,
                                                        float* __restrict__ final_out){
  int b = blockIdx.y, ch = blockIdx.x, tid = threadIdx.x;
  __shared__ float red[1024];
  float mv = (tid < 782) ? mpart[(size_t)b*782 + tid] : -1e30f;
  red[tid] = mv; __syncthreads();
  for (int s = 512; s > 0; s >>= 1){ if (tid < s) red[tid] = fmaxf(red[tid], red[tid+s]); __syncthreads(); }
  float M = red[0]; __syncthreads();
  float sv = (tid < 782) ? spart[(size_t)b*782 + tid] * __expf(mv - M) : 0.f;
  red[tid] = sv; __syncthreads();
  for (int s = 512; s > 0; s >>= 1){ if (tid < s) red[tid] += red[tid+s]; __syncthreads(); }
  float scale = p_gen[b]/red[0];
  const float* lrow = &logits[(size_t)b*Vn];
  float* frow = &final_out[(size_t)b*VEXTn];
  int v0 = ch*6250;
  for (int v = v0 + tid; v < v0 + 6250; v += 1024) frow[v] = __expf(lrow[v] - M)*scale;
  if (ch == 7)
    for (int v = Vn + tid; v < VEXTn; v += 1024) frow[v] = 0.f;
}

__global__ __launch_bounds__(512) void k_scatter_add(const float* __restrict__ p_gen, const int* __restrict__ ebev,
                                                     const float* __restrict__ at_ws, float* __restrict__ final_out){
  int b = blockIdx.x, tid = threadIdx.x;
  if (tid < 400){
    float add = (1.f - p_gen[b]) * at_ws[b*400+tid];
    atomicAdd(&final_out[(size_t)b*VEXTn + ebev[b*400+tid]], add);
  }
}

__global__ __launch_bounds__(256) void k_prevs(const float* __restrict__ prev_s, const float* __restrict__ h,
                                               float* __restrict__ o_prevs){
  int i = blockIdx.x*256 + threadIdx.x;
  int b = i / (51*512);
  int rem = i - b*51*512;
  int tau = rem >> 9, j = rem & 511;
  o_prevs[i] = (tau < 50) ? prev_s[((size_t)b*50 + tau)*512 + j] : h[b*512+j];
}

extern "C" void kernel_launch(void* const* d_in, const int* in_sizes, int n_in,
                              void* d_out, int out_size, void* d_ws, size_t ws_size,
                              hipStream_t stream)
{
  const float* x_t    = (const float*)d_in[0];
  const float* s_h    = (const float*)d_in[1];
  const float* s_c    = (const float*)d_in[2];
  const float* enc    = (const float*)d_in[3];
  const float* mask   = (const float*)d_in[4];
  const float* ct_e   = (const float*)d_in[5];
  const float* sumts  = (const float*)d_in[7];
  const float* prev_s = (const float*)d_in[8];
  const int*   ebev   = (const int*)d_in[9];
  const float* W_xc   = (const float*)d_in[10];
  const float* b_xc   = (const float*)d_in[11];
  const float* W_ih   = (const float*)d_in[12];
  const float* W_hh   = (const float*)d_in[13];
  const float* b_ih   = (const float*)d_in[14];
  const float* b_hh   = (const float*)d_in[15];
  const float* We_h   = (const float*)d_in[16];
  const float* We_s   = (const float*)d_in[17];
  const float* be_s   = (const float*)d_in[18];
  const float* ve     = (const float*)d_in[19];
  const float* Ws_h   = (const float*)d_in[20];
  const float* bs_h   = (const float*)d_in[21];
  const float* vs1    = (const float*)d_in[22];
  const float* vs2    = (const float*)d_in[23];
  const float* Wd_prev= (const float*)d_in[24];
  const float* Wd_s   = (const float*)d_in[25];
  const float* bd_s   = (const float*)d_in[26];
  const float* vd     = (const float*)d_in[27];
  const float* w_pg_em  = (const float*)d_in[28];
  const float* w_pg_cte = (const float*)d_in[29];
  const float* w_pg_ctd = (const float*)d_in[30];
  const float* w_pg_st  = (const float*)d_in[31];
  const float* b_pg_st  = (const float*)d_in[32];
  const float* W_V    = (const float*)d_in[33];
  const float* b_V    = (const float*)d_in[34];
  const float* W_V1   = (const float*)d_in[35];
  const float* b_V1   = (const float*)d_in[36];
  (void)in_sizes; (void)n_in; (void)out_size; (void)ws_size;

  float* out = (float*)d_out;
  float* o_final = out;
  float* o_h     = out + 3206400;
  float* o_c     = out + 3239168;
  float* o_cte   = out + 3271936;
  float* o_au    = out + 3337472;
  float* o_et2   = out + 3363072;
  float* o_sumn  = out + 3428608;
  float* o_prevs = out + 3454208;

  char* ws = (char*)d_ws;
  // zeroed accumulators
  float* et_raw    = (float*)(ws + 0);
  float* au_raw    = (float*)(ws + 102400);
  float* et2_acc   = (float*)(ws + 204800);
  float* x_acc     = (float*)(ws + 466944);
  float* gates_acc = (float*)(ws + 532480);
  float* qe_acc    = (float*)(ws + 1056768);
  float* qd_acc    = (float*)(ws + 1318912);
  float* ov_acc    = (float*)(ws + 1449984);    // end 1581056
  // scratch
  float* at_ws   = (float*)(ws + 1581056);
  float* ct_d    = (float*)(ws + 1683456);
  float* p_gen   = (float*)(ws + 1814528);
  float* tmp_ed  = (float*)(ws + 1900544);      // 6.55 MB (shares region with logits)
  float* logits  = (float*)(ws + 1900544);      // 12.8 MB -> end 14700544
  unsigned short* out_vec_bf = (unsigned short*)(ws + 14700544);
  unsigned short* enc_bf  = (unsigned short*)(ws + 14780416);   // 52.4 MB
  unsigned short* Bt_bf   = (unsigned short*)(ws + 67209216);   // 4 MB
  // softmax partials alias the (already-consumed) gemv accumulator region
  float* mpart = (float*)(ws + 466944);         // 64*782*4 = 200192 B
  float* spart = (float*)(ws + 667136);         // 200192 B -> end 867328

  hipMemsetAsync(ws, 0, 1581056, stream);
  k_conv_enc<<<25600, 256, 0, stream>>>(enc, enc_bf);
  k_transpose<<<dim3(32,32,2), 256, 0, stream>>>(We_h, Ws_h, Bt_bf);
  k_gemv_x<<<dim3(1,64,5), 256, 0, stream>>>(x_t, ct_e, W_xc, x_acc);
  k_gemv_gates<<<dim3(8,64,3), 256, 0, stream>>>(x_acc, b_xc, s_h, W_ih, W_hh, gates_acc);
  k_lstm_act<<<dim3(2,64), 256, 0, stream>>>(gates_acc, b_ih, b_hh, s_c, o_h, o_c);
  k_gemv_qe<<<dim3(4,64,4), 256, 0, stream>>>(o_h, o_c, We_s, qe_acc);
  k_gemv_qd<<<dim3(2,64,2), 256, 0, stream>>>(o_h, Wd_s, qd_acc);
  k_gemm_big<<<dim3(16,200), 256, 0, stream>>>(enc_bf, Bt_bf, qe_acc, be_s, bs_h, ve, vs1, vs2,
                                               et_raw, au_raw, et2_acc);
  k_attn_norm<<<64, 512, 0, stream>>>(et_raw, au_raw, et2_acc, sumts, mask, o_sumn, o_au, o_et2, at_ws);
  k_cte<<<dim3(2,64), 256, 0, stream>>>(enc_bf, at_ws, o_cte);
  k_ed<<<dim3(4,64), 256, 0, stream>>>(prev_s, Wd_prev, qd_acc, bd_s, vd, tmp_ed);
  k_ctd_pgen<<<64, 512, 0, stream>>>(tmp_ed, prev_s, o_cte, o_et2, o_h, o_c,
                                     w_pg_cte, w_pg_ctd, w_pg_st, w_pg_em, b_pg_st, ct_d, p_gen);
  k_gemv_outvec<<<dim3(2,64,6), 256, 0, stream>>>(o_h, o_cte, ct_d, o_et2, W_V, ov_acc);
  k_outvec_fin<<<128, 256, 0, stream>>>(ov_acc, b_V, out_vec_bf);
  k_logits_mfma<<<782, 256, 0, stream>>>(out_vec_bf, W_V1, b_V1, logits, mpart, spart);
  k_softmax_write<<<dim3(8,64), 1024, 0, stream>>>(logits, mpart, spart, p_gen, o_final);
  k_scatter_add<<<64, 512, 0, stream>>>(p_gen, ebev, at_ws, o_final);
  k_prevs<<<6528, 256, 0, stream>>>(prev_s, o_h, o_prevs);
}

// Round 3
// 719.677 us; speedup vs baseline: 1.2708x; 1.2103x over previous
//
#include <hip/hip_runtime.h>
#include <stdint.h>

#define Bn 64
#define Tn 400
#define Hn 512
#define En 256
#define Vn 50000
#define NOOVn 100
#define TPn 50
#define H2n 1024
#define VEXTn (Vn+NOOVn)  // 50100

typedef __bf16 bf16x8 __attribute__((ext_vector_type(8)));
typedef float  f32x4  __attribute__((ext_vector_type(4)));

__device__ __forceinline__ float sigf(float x){ return 1.0f/(1.0f+__expf(-x)); }
__device__ __forceinline__ float tanh_fast(float x){
  float e = __expf(2.0f*x);
  return (e-1.0f)/(e+1.0f);
}

__device__ __forceinline__ unsigned short f2bf(float f){
  union { float f; uint32_t u; } v; v.f = f;
  uint32_t r = v.u + 0x7FFFu + ((v.u >> 16) & 1u);
  return (unsigned short)(r >> 16);
}
__device__ __forceinline__ float bf2f(unsigned short s){
  union { uint32_t u; float f; } v; v.u = ((uint32_t)s) << 16;
  return v.f;
}

__device__ __forceinline__ void async16(const void* g, void* l){
  __builtin_amdgcn_global_load_lds((__attribute__((address_space(1))) void*)g,
                                   (__attribute__((address_space(3))) void*)l, 16, 0, 0);
}

// ---------------- conversions (enc->bf16 fused with weight transpose) ----------------
// blocks [0,25600): enc conversion; [25600,27648): Bt[n][k] = W[k][n] transpose+convert
__global__ __launch_bounds__(256) void k_conv_enc(const float* __restrict__ enc, unsigned short* __restrict__ out,
                                                  const float* __restrict__ W1, const float* __restrict__ W2,
                                                  unsigned short* __restrict__ Bt){
  __shared__ float tile[32][33];
  const int bx = blockIdx.x;
  if (bx < 25600){
    int i = bx*256 + threadIdx.x;
    float4 v = ((const float4*)enc)[i];
    ushort4 r;
    r.x = f2bf(v.x); r.y = f2bf(v.y); r.z = f2bf(v.z); r.w = f2bf(v.w);
    ((ushort4*)out)[i] = r;
    return;
  }
  int t = bx - 25600;
  const float* W = (t >> 10) ? W2 : W1;
  int nbase = (t >> 10) * 1024;
  int rem = t & 1023;
  int n0 = (rem & 31)*32, k0 = (rem >> 5)*32;
  int tx = threadIdx.x & 31, ty = threadIdx.x >> 5;  // ty 0..7
  for (int i = 0; i < 32; i += 8)
    tile[ty+i][tx] = W[(size_t)(k0+ty+i)*1024 + n0+tx];
  __syncthreads();
  for (int i = 0; i < 32; i += 8)
    Bt[(size_t)(nbase+n0+ty+i)*1024 + k0+tx] = f2bf(tile[tx][ty+i]);
}

// ---------------- split-K GEMV chain (M=64, fp32 atomics) ----------------
__global__ __launch_bounds__(256) void k_gemv_x(const float* __restrict__ x_t, const float* __restrict__ ct_e,
                                                const float* __restrict__ W_xc, float* __restrict__ x_acc){
  int n = threadIdx.x;
  int b = blockIdx.y;
  int k0 = blockIdx.z*256;        // z 0..4 (K=1280)
  float acc = 0.f;
  #pragma unroll 4
  for (int kk = 0; kk < 256; ++kk){
    int k = k0 + kk;
    float a = (k < 256) ? x_t[b*256+k] : ct_e[b*1024 + k - 256];
    acc += a * W_xc[(size_t)k*256 + n];
  }
  atomicAdd(&x_acc[b*256+n], acc);
}

__global__ __launch_bounds__(256) void k_gemv_gates(const float* __restrict__ x_acc, const float* __restrict__ b_xc,
                                                    const float* __restrict__ s_h,
                                                    const float* __restrict__ W_ih, const float* __restrict__ W_hh,
                                                    float* __restrict__ gates_acc){
  int n = blockIdx.x*256 + threadIdx.x;  // 0..2047
  int b = blockIdx.y;
  int k0 = blockIdx.z*256;               // z 0..2 (K=768)
  float acc = 0.f;
  #pragma unroll 4
  for (int kk = 0; kk < 256; ++kk){
    int k = k0 + kk;
    float a; const float* wrow;
    if (k < 256){ a = x_acc[b*256+k] + b_xc[k]; wrow = &W_ih[(size_t)k*2048]; }
    else        { a = s_h[b*512 + k-256];       wrow = &W_hh[(size_t)(k-256)*2048]; }
    acc += a * wrow[n];
  }
  atomicAdd(&gates_acc[(size_t)b*2048 + n], acc);
}

__global__ __launch_bounds__(256) void k_lstm_act(const float* __restrict__ gates_acc,
                                                  const float* __restrict__ b_ih, const float* __restrict__ b_hh,
                                                  const float* __restrict__ s_c,
                                                  float* __restrict__ h_out, float* __restrict__ c_out){
  int b = blockIdx.y;
  int j = blockIdx.x*256 + threadIdx.x;
  const float* g = &gates_acc[(size_t)b*2048];
  float gi = g[j]      + b_ih[j]      + b_hh[j];
  float gf = g[512+j]  + b_ih[512+j]  + b_hh[512+j];
  float gg = g[1024+j] + b_ih[1024+j] + b_hh[1024+j];
  float go = g[1536+j] + b_ih[1536+j] + b_hh[1536+j];
  float c = sigf(gf)*s_c[b*512+j] + sigf(gi)*tanh_fast(gg);
  float h = sigf(go)*tanh_fast(c);
  h_out[b*512+j] = h;
  c_out[b*512+j] = c;
}

// qe-GEMV + qd-GEMV + prev_s concat, one launch (all depend only on h/c)
// blocks [0,1024): qe; [1024,1280): qd; [1280,7808): prevs copy
__global__ __launch_bounds__(256) void k_qqp(const float* __restrict__ h, const float* __restrict__ c,
                                             const float* __restrict__ We_s, float* __restrict__ qe_acc,
                                             const float* __restrict__ Wd_s, float* __restrict__ qd_acc,
                                             const float* __restrict__ prev_s, float* __restrict__ o_prevs){
  const int bx = blockIdx.x, tid = threadIdx.x;
  if (bx < 1024){
    int x = bx & 3, b = (bx >> 2) & 63, z = bx >> 8;
    int n = x*256 + tid, k0 = z*256;
    float acc = 0.f;
    #pragma unroll 4
    for (int kk = 0; kk < 256; ++kk){
      int k = k0 + kk;
      float a = (k < 512) ? h[b*512+k] : c[b*512 + k-512];
      acc += a * We_s[(size_t)k*1024 + n];
    }
    atomicAdd(&qe_acc[b*1024+n], acc);
  } else if (bx < 1280){
    int j = bx - 1024;
    int x = j & 1, b = (j >> 1) & 63, z = j >> 7;
    int n = x*256 + tid, k0 = z*256;
    float acc = 0.f;
    #pragma unroll 4
    for (int kk = 0; kk < 256; ++kk){
      int k = k0 + kk;
      acc += h[b*512+k] * Wd_s[(size_t)k*512 + n];
    }
    atomicAdd(&qd_acc[b*512+n], acc);
  } else {
    int i = (bx - 1280)*256 + tid;
    int b = i / (51*512);
    int rem = i - b*51*512;
    int tau = rem >> 9, jj = rem & 511;
    o_prevs[i] = (tau < 50) ? prev_s[((size_t)b*50 + tau)*512 + jj] : h[b*512+jj];
  }
}

__global__ __launch_bounds__(256) void k_gemv_outvec(const float* __restrict__ h, const float* __restrict__ cte,
                                                     const float* __restrict__ ctd, const float* __restrict__ et2,
                                                     const float* __restrict__ W_V, float* __restrict__ ov_acc){
  int n = blockIdx.x*256 + threadIdx.x;
  int b = blockIdx.y;
  int z = blockIdx.z;
  const float* base;
  switch(z){
    case 0:  base = &h[b*512];        break;
    case 1:  base = &cte[b*1024];     break;
    case 2:  base = &cte[b*1024+512]; break;
    case 3:  base = &ctd[b*512];      break;
    case 4:  base = &et2[b*1024];     break;
    default: base = &et2[b*1024+512]; break;
  }
  const float* wrow = &W_V[(size_t)z*512*512];
  float acc = 0.f;
  #pragma unroll 4
  for (int kk = 0; kk < 512; ++kk)
    acc += base[kk] * wrow[(size_t)kk*512 + n];
  atomicAdd(&ov_acc[b*512+n], acc);
}

// ---------------- the big fused dual-GEMM (m97 pattern + XOR-swizzled LDS) ----------------
// blocks [0,256): intra-decoder ed GEMM (VALU-bound, hides in gemm's stall cycles)
// blocks [256,3456): 128^2 MFMA tiles with bijective XCD chunk swizzle (A-panel
// locality: each XCD L2 fetches each A-panel once).
__global__ __launch_bounds__(256,4) void k_gemm_big(
    const unsigned short* __restrict__ Abf,   // [25600][1024]
    const unsigned short* __restrict__ Btbf,  // [2048][1024]
    const float* __restrict__ q_e,
    const float* __restrict__ be_s,
    const float* __restrict__ bs_h, const float* __restrict__ ve,
    const float* __restrict__ vs1,  const float* __restrict__ vs2,
    float* __restrict__ et_raw, float* __restrict__ au_raw, float* __restrict__ et2_acc,
    const float* __restrict__ prev_s, const float* __restrict__ Wd_prev,
    const float* __restrict__ q_d, const float* __restrict__ bd_s,
    const float* __restrict__ vd, float* __restrict__ tmp_ed)
{
  __shared__ __align__(16) unsigned short As[128*64];
  __shared__ __align__(16) unsigned short Bs[128*64];
  __shared__ float bias2_s[2][128];
  __shared__ float vv_s[128];
  __shared__ float rowW_s[128];
  __shared__ unsigned char rowSel_s[128];

  const int tid = threadIdx.x;
  const int linb = blockIdx.x;

  if (linb < 256){
    // ---- intra-decoder attention scores (was k_ed) ----
    int b = linb >> 2, ex = linb & 3;
    int j = (ex & 1)*256 + tid;
    int taub = (ex >> 1)*25;
    float acc[25];
    #pragma unroll
    for (int t = 0; t < 25; ++t) acc[t] = 0.f;
    const float* ps = &prev_s[((size_t)b*50 + taub)*512];
    for (int k = 0; k < 512; ++k){
      float wv = Wd_prev[(size_t)k*512 + j];
      #pragma unroll
      for (int t = 0; t < 25; ++t) acc[t] += ps[(size_t)t*512 + k] * wv;
    }
    float qv = q_d[b*512+j] + bd_s[j], vdj = vd[j];
    #pragma unroll
    for (int t = 0; t < 25; ++t)
      tmp_ed[((size_t)b*50 + taub + t)*512 + j] = tanh_fast(acc[t] + qv) * vdj;
    return;
  }

  const int g = linb - 256;                       // 0..3199, 3200 = 8*400
  const int swz = (g & 7)*400 + (g >> 3);         // bijective XCD chunk swizzle
  const int bn = swz & 15, bm = swz >> 4;         // bm-major within each XCD

  const int r0  = bm*128;
  const int n0g = bn*128;
  const bool etmode = (n0g < 1024);
  const int dbase = etmode ? n0g : (n0g - 1024);
  const int b_lo = r0/400;
  const int b_hi = min(b_lo+1, 63);
  const bool bcross = (r0/400) != ((r0+127)/400);

  if (tid < 128){
    int r = r0 + tid;
    int bb = r/400;
    rowSel_s[tid] = (unsigned char)(bb - b_lo);
    rowW_s[tid]   = vs2[r - bb*400];
    vv_s[tid]     = etmode ? ve[dbase+tid] : vs1[dbase+tid];
    bias2_s[0][tid] = etmode ? (q_e[b_lo*1024 + dbase + tid] + be_s[dbase+tid]) : bs_h[dbase+tid];
    bias2_s[1][tid] = etmode ? (q_e[b_hi*1024 + dbase + tid] + be_s[dbase+tid]) : bs_h[dbase+tid];
  }

  const int w = tid >> 6, lane = tid & 63;
  const int wm = w & 1, wn = w >> 1;
  const int lr = lane & 15, lq = lane >> 4;

  // XOR-swizzled staging: LDS slot (row, j) holds global chunk j ^ (row&7)
  const int srow = lane >> 3;
  const int c_g  = (lane & 7) ^ (srow & 7);      // swizzled global chunk for this lane
  const unsigned short* gA0 = Abf  + (size_t)(r0  + w*32 + srow)*1024 + c_g*8;
  const unsigned short* gB0 = Btbf + (size_t)(n0g + w*32 + srow)*1024 + c_g*8;
  unsigned short* lA0 = As + w*32*64;
  unsigned short* lB0 = Bs + w*32*64;

  f32x4 acc[4][4];
  #pragma unroll
  for (int i = 0; i < 4; ++i)
    #pragma unroll
    for (int j = 0; j < 4; ++j){ acc[i][j][0]=0.f; acc[i][j][1]=0.f; acc[i][j][2]=0.f; acc[i][j][3]=0.f; }

  for (int kt = 0; kt < 16; ++kt){
    __syncthreads();
    #pragma unroll
    for (int q = 0; q < 4; ++q){
      async16(gA0 + (size_t)q*8*1024 + kt*64, lA0 + q*512);
      async16(gB0 + (size_t)q*8*1024 + kt*64, lB0 + q*512);
    }
    __syncthreads();
    #pragma unroll
    for (int kk = 0; kk < 2; ++kk){
      const int slot8 = ((kk*4 + lq) ^ (lr & 7)) * 8;   // de-swizzled read
      bf16x8 a[4], b[4];
      #pragma unroll
      for (int i = 0; i < 4; ++i){
        a[i] = *(const bf16x8*)&As[(wm*64 + i*16 + lr)*64 + slot8];
        b[i] = *(const bf16x8*)&Bs[(wn*64 + i*16 + lr)*64 + slot8];
      }
      #pragma unroll
      for (int mt = 0; mt < 4; ++mt)
        #pragma unroll
        for (int nt = 0; nt < 4; ++nt)
          acc[mt][nt] = __builtin_amdgcn_mfma_f32_16x16x32_bf16(a[mt], b[nt], acc[mt][nt], 0, 0, 0);
    }
  }

  // ---- register epilogue ----
  float vvr[4], bias0[4], bias1[4];
  #pragma unroll
  for (int nt = 0; nt < 4; ++nt){
    int n = wn*64 + nt*16 + lr;
    vvr[nt]   = vv_s[n];
    bias0[nt] = bias2_s[0][n];
    bias1[nt] = bias2_s[1][n];
  }

  float rowdot[16];
  float colacc[4][2];
  #pragma unroll
  for (int nt = 0; nt < 4; ++nt){ colacc[nt][0]=0.f; colacc[nt][1]=0.f; }

  #pragma unroll
  for (int mt = 0; mt < 4; ++mt){
    #pragma unroll
    for (int v = 0; v < 4; ++v){
      int m = wm*64 + mt*16 + lq*4 + v;
      int sel = rowSel_s[m];
      float rw = rowW_s[m];
      float rd = 0.f;
      #pragma unroll
      for (int nt = 0; nt < 4; ++nt){
        float t = tanh_fast(acc[mt][nt][v] + (sel ? bias1[nt] : bias0[nt]));
        rd += t * vvr[nt];
        if (!etmode) colacc[nt][sel] += t * rw;
      }
      rowdot[mt*4+v] = rd;
    }
  }

  #pragma unroll
  for (int i = 0; i < 16; ++i){
    float s = rowdot[i];
    s += __shfl_xor(s,1); s += __shfl_xor(s,2); s += __shfl_xor(s,4); s += __shfl_xor(s,8);
    rowdot[i] = s;
  }
  if (lr == 0){
    float* dst = etmode ? et_raw : au_raw;
    #pragma unroll
    for (int i = 0; i < 16; ++i){
      int m = wm*64 + (i>>2)*16 + lq*4 + (i&3);
      atomicAdd(&dst[r0+m], rowdot[i]);
    }
  }

  if (!etmode){
    #pragma unroll
    for (int nt = 0; nt < 4; ++nt){
      #pragma unroll
      for (int s = 0; s < 2; ++s){
        float c = colacc[nt][s];
        c += __shfl_xor(c,16); c += __shfl_xor(c,32);
        if (lq == 0 && (s == 0 || bcross)){
          int n = wn*64 + nt*16 + lr;
          atomicAdd(&et2_acc[(b_lo+s)*1024 + dbase + n], c);
        }
      }
    }
  }
}

// ---------------- attention normalizations ----------------
__global__ __launch_bounds__(512) void k_attn_norm(const float* __restrict__ et_raw, const float* __restrict__ au_raw,
                                                   const float* __restrict__ et2_acc,
                                                   const float* __restrict__ sumts, const float* __restrict__ mask,
                                                   float* __restrict__ o_sumn, float* __restrict__ o_au,
                                                   float* __restrict__ o_et2, float* __restrict__ at_ws){
  int b = blockIdx.x, tid = threadIdx.x;
  __shared__ float red[512];
  float w = 0.f;
  if (tid < 400){
    float e  = __expf(et_raw[b*400+tid]);
    float st = sumts[b*400+tid];
    o_sumn[b*400+tid] = st + e;
    w = (e/st) * mask[b*400+tid];
  }
  red[tid] = w; __syncthreads();
  for (int s = 256; s > 0; s >>= 1){ if (tid < s) red[tid] += red[tid+s]; __syncthreads(); }
  float invw = 1.0f/red[0];
  __syncthreads();
  if (tid < 400) at_ws[b*400+tid] = w*invw;

  float a = 0.f;
  if (tid < 400) a = sigf(au_raw[b*400+tid]) * mask[b*400+tid];
  red[tid] = a; __syncthreads();
  for (int s = 256; s > 0; s >>= 1){ if (tid < s) red[tid] += red[tid+s]; __syncthreads(); }
  float inva = 1.0f/red[0];
  if (tid < 400) o_au[b*400+tid] = a*inva;

  for (int d = tid; d < 1024; d += 512) o_et2[b*1024+d] = sigf(et2_acc[b*1024+d]);
}

// vectorized: 2 bf16 per lane per t-step (uint load)
__global__ __launch_bounds__(256) void k_cte(const unsigned short* __restrict__ Abf, const float* __restrict__ at_ws,
                                             float* __restrict__ o_cte){
  int b = blockIdx.y;
  int d0 = (blockIdx.x*256 + threadIdx.x)*2;
  float a0 = 0.f, a1 = 0.f;
  for (int t = 0; t < 400; ++t){
    float w = at_ws[b*400+t];
    uint32_t v = *(const uint32_t*)&Abf[((size_t)(b*400+t))*1024 + d0];
    a0 += w * bf2f((unsigned short)(v & 0xffffu));
    a1 += w * bf2f((unsigned short)(v >> 16));
  }
  float2 r; r.x = a0; r.y = a1;
  *(float2*)&o_cte[b*1024 + d0] = r;
}

// ctd + p_gen fused (one block per b, 512 threads)
__global__ __launch_bounds__(512) void k_ctd_pgen(const float* __restrict__ tmp_ed, const float* __restrict__ prev_s,
                                                  const float* __restrict__ cte, const float* __restrict__ et2,
                                                  const float* __restrict__ h, const float* __restrict__ c,
                                                  const float* __restrict__ w_pg_cte, const float* __restrict__ w_pg_ctd,
                                                  const float* __restrict__ w_pg_st, const float* __restrict__ w_pg_em,
                                                  const float* __restrict__ b_pg_st,
                                                  float* __restrict__ ct_d, float* __restrict__ p_gen){
  int b = blockIdx.x, tid = threadIdx.x;
  __shared__ float ed_s[50];
  __shared__ float ad_s[50];
  __shared__ float red[512];
  if (tid < 400){
    int tau = tid >> 3, part = tid & 7;
    const float* tp = &tmp_ed[((size_t)b*50 + tau)*512 + part*64];
    float p = 0.f;
    for (int j = 0; j < 64; ++j) p += tp[j];
    p += __shfl_xor(p, 1); p += __shfl_xor(p, 2); p += __shfl_xor(p, 4);
    if (part == 0) ed_s[tau] = p;
  }
  __syncthreads();
  if (tid == 0){
    float mx = -1e30f;
    for (int t = 0; t < 50; ++t) mx = fmaxf(mx, ed_s[t]);
    float se = 0.f;
    for (int t = 0; t < 50; ++t){ float e = __expf(ed_s[t]-mx); ad_s[t] = e; se += e; }
    float inv = 1.f/se;
    for (int t = 0; t < 50; ++t) ad_s[t] *= inv;
  }
  __syncthreads();
  float acc = 0.f;
  for (int t = 0; t < 50; ++t) acc += ad_s[t]*prev_s[((size_t)b*50 + t)*512 + tid];
  ct_d[b*512+tid] = acc;

  // p_gen partials
  float s = acc*w_pg_ctd[tid] + h[b*512+tid]*w_pg_st[tid] + c[b*512+tid]*w_pg_st[512+tid];
  s += cte[b*1024+tid]*w_pg_cte[tid] + cte[b*1024+512+tid]*w_pg_cte[512+tid];
  s += et2[b*1024+tid]*w_pg_em[tid]  + et2[b*1024+512+tid]*w_pg_em[512+tid];
  red[tid] = s; __syncthreads();
  for (int k = 256; k > 0; k >>= 1){ if (tid < k) red[tid] += red[tid+k]; __syncthreads(); }
  if (tid == 0) p_gen[b] = sigf(red[0] + b_pg_st[0]);
}

// ---------------- logits MFMA: fused A-convert (ov_acc+b_V -> bf16), W_V1 transpose+convert,
// and softmax partials ----------------
__global__ __launch_bounds__(256,4) void k_logits_mfma(const float* __restrict__ ov_acc,  // [64][512] fp32
                                                       const float* __restrict__ b_V,    // [512]
                                                       const float* __restrict__ W_V1,   // [512][50000] fp32
                                                       const float* __restrict__ b_V1, float* __restrict__ logits,
                                                       float* __restrict__ mpart, float* __restrict__ spart){
  __shared__ __align__(16) unsigned short As[64][72];
  __shared__ __align__(16) unsigned short Bs[64][72];
  __shared__ float pred[4][64];
  __shared__ float gmax[64];
  const int tid = threadIdx.x;
  const int n0 = blockIdx.x*64;
  const int w = tid >> 6, lane = tid & 63;
  const int lr = lane & 15, lq = lane >> 4;

  const int am = tid >> 2, ac = tid & 3;        // A staging: m, chunk
  const int sn = tid & 63, skg = tid >> 6;      // B staging: n, k-group
  const int bnc = (n0 + sn < Vn) ? (n0 + sn) : (Vn - 1);

  f32x4 acc[4];
  #pragma unroll
  for (int i = 0; i < 4; ++i){ acc[i][0]=0.f; acc[i][1]=0.f; acc[i][2]=0.f; acc[i][3]=0.f; }

  for (int kt = 0; kt < 8; ++kt){
    const int k0 = kt*64;
    __syncthreads();
    // A tile: fp32 ov_acc + b_V -> bf16 padded LDS (was a separate k_outvec_fin pass)
    #pragma unroll
    for (int s = 0; s < 2; ++s){
      int ke = k0 + (ac + 4*s)*8;
      float4 fa  = *(const float4*)&ov_acc[am*512 + ke];
      float4 fa2 = *(const float4*)&ov_acc[am*512 + ke + 4];
      float4 fb  = *(const float4*)&b_V[ke];
      float4 fb2 = *(const float4*)&b_V[ke + 4];
      ushort4 u0, u1;
      u0.x = f2bf(fa.x+fb.x);  u0.y = f2bf(fa.y+fb.y);  u0.z = f2bf(fa.z+fb.z);  u0.w = f2bf(fa.w+fb.w);
      u1.x = f2bf(fa2.x+fb2.x); u1.y = f2bf(fa2.y+fb2.y); u1.z = f2bf(fa2.z+fb2.z); u1.w = f2bf(fa2.w+fb2.w);
      *(ushort4*)&As[am][(ac + 4*s)*8]     = u0;
      *(ushort4*)&As[am][(ac + 4*s)*8 + 4] = u1;
    }
    // B tile: fp32 [k][n] -> bf16 LDS [n][k]
    #pragma unroll
    for (int jq = 0; jq < 4; ++jq){
      int kb = k0 + skg*16 + jq*4;
      float f0 = W_V1[(size_t)(kb+0)*Vn + bnc];
      float f1 = W_V1[(size_t)(kb+1)*Vn + bnc];
      float f2 = W_V1[(size_t)(kb+2)*Vn + bnc];
      float f3 = W_V1[(size_t)(kb+3)*Vn + bnc];
      ushort4 u; u.x = f2bf(f0); u.y = f2bf(f1); u.z = f2bf(f2); u.w = f2bf(f3);
      *(ushort4*)&Bs[sn][skg*16 + jq*4] = u;
    }
    __syncthreads();
    #pragma unroll
    for (int kk = 0; kk < 2; ++kk){
      bf16x8 a[4], b;
      #pragma unroll
      for (int i = 0; i < 4; ++i)
        a[i] = *(const bf16x8*)&As[i*16 + lr][kk*32 + lq*8];
      b = *(const bf16x8*)&Bs[w*16 + lr][kk*32 + lq*8];
      #pragma unroll
      for (int mt = 0; mt < 4; ++mt)
        acc[mt] = __builtin_amdgcn_mfma_f32_16x16x32_bf16(a[mt], b, acc[mt], 0, 0, 0);
    }
  }

  const int n = n0 + w*16 + lr;
  const bool nok = (n < Vn);
  const float bb = nok ? b_V1[n] : 0.f;

  // store logits + per-row column-max partial (butterfly over lr = cols)
  #pragma unroll
  for (int mt = 0; mt < 4; ++mt)
    #pragma unroll
    for (int v = 0; v < 4; ++v){
      int m = mt*16 + lq*4 + v;
      float val = nok ? (acc[mt][v] + bb) : -1e30f;
      if (nok) logits[(size_t)m*Vn + n] = val;
      float t = val;
      t = fmaxf(t, __shfl_xor(t,1)); t = fmaxf(t, __shfl_xor(t,2));
      t = fmaxf(t, __shfl_xor(t,4)); t = fmaxf(t, __shfl_xor(t,8));
      if (lr == 0) pred[w][m] = t;
    }
  __syncthreads();
  if (tid < 64)
    gmax[tid] = fmaxf(fmaxf(pred[0][tid], pred[1][tid]), fmaxf(pred[2][tid], pred[3][tid]));
  __syncthreads();

  // per-row sum-of-exp partial
  #pragma unroll
  for (int mt = 0; mt < 4; ++mt)
    #pragma unroll
    for (int v = 0; v < 4; ++v){
      int m = mt*16 + lq*4 + v;
      float e = nok ? __expf(acc[mt][v] + bb - gmax[m]) : 0.f;
      e += __shfl_xor(e,1); e += __shfl_xor(e,2);
      e += __shfl_xor(e,4); e += __shfl_xor(e,8);
      if (lr == 0) pred[w][m] = e;
    }
  __syncthreads();
  if (tid < 64){
    float s = pred[0][tid] + pred[1][tid] + pred[2][tid] + pred[3][tid];
    mpart[(size_t)tid*782 + blockIdx.x] = gmax[tid];
    spart[(size_t)tid*782 + blockIdx.x] = s;
  }
}

// combine 782 per-block partials per row, write final probs for a 6250-col slice
__global__ __launch_bounds__(1024) void k_softmax_write(const float* __restrict__ logits,
                                                        const float* __restrict__ mpart, const float* __restrict__ spart,
                                                        const float* __restrict__ p_gen,
                                                        float* __restrict__ final_out){
  int b = blockIdx.y, ch = blockIdx.x, tid = threadIdx.x;
  __shared__ float red[1024];
  float mv = (tid < 782) ? mpart[(size_t)b*782 + tid] : -1e30f;
  red[tid] = mv; __syncthreads();
  for (int s = 512; s > 0; s >>= 1){ if (tid < s) red[tid] = fmaxf(red[tid], red[tid+s]); __syncthreads(); }
  float M = red[0]; __syncthreads();
  float sv = (tid < 782) ? spart[(size_t)b*782 + tid] * __expf(mv - M) : 0.f;
  red[tid] = sv; __syncthreads();
  for (int s = 512; s > 0; s >>= 1){ if (tid < s) red[tid] += red[tid+s]; __syncthreads(); }
  float scale = p_gen[b]/red[0];
  const float* lrow = &logits[(size_t)b*Vn];
  float* frow = &final_out[(size_t)b*VEXTn];
  int v0 = ch*6250;
  for (int v = v0 + tid; v < v0 + 6250; v += 1024) frow[v] = __expf(lrow[v] - M)*scale;
  if (ch == 7)
    for (int v = Vn + tid; v < VEXTn; v += 1024) frow[v] = 0.f;
}

__global__ __launch_bounds__(512) void k_scatter_add(const float* __restrict__ p_gen, const int* __restrict__ ebev,
                                                     const float* __restrict__ at_ws, float* __restrict__ final_out){
  int b = blockIdx.x, tid = threadIdx.x;
  if (tid < 400){
    float add = (1.f - p_gen[b]) * at_ws[b*400+tid];
    atomicAdd(&final_out[(size_t)b*VEXTn + ebev[b*400+tid]], add);
  }
}

extern "C" void kernel_launch(void* const* d_in, const int* in_sizes, int n_in,
                              void* d_out, int out_size, void* d_ws, size_t ws_size,
                              hipStream_t stream)
{
  const float* x_t    = (const float*)d_in[0];
  const float* s_h    = (const float*)d_in[1];
  const float* s_c    = (const float*)d_in[2];
  const float* enc    = (const float*)d_in[3];
  const float* mask   = (const float*)d_in[4];
  const float* ct_e   = (const float*)d_in[5];
  const float* sumts  = (const float*)d_in[7];
  const float* prev_s = (const float*)d_in[8];
  const int*   ebev   = (const int*)d_in[9];
  const float* W_xc   = (const float*)d_in[10];
  const float* b_xc   = (const float*)d_in[11];
  const float* W_ih   = (const float*)d_in[12];
  const float* W_hh   = (const float*)d_in[13];
  const float* b_ih   = (const float*)d_in[14];
  const float* b_hh   = (const float*)d_in[15];
  const float* We_h   = (const float*)d_in[16];
  const float* We_s   = (const float*)d_in[17];
  const float* be_s   = (const float*)d_in[18];
  const float* ve     = (const float*)d_in[19];
  const float* Ws_h   = (const float*)d_in[20];
  const float* bs_h   = (const float*)d_in[21];
  const float* vs1    = (const float*)d_in[22];
  const float* vs2    = (const float*)d_in[23];
  const float* Wd_prev= (const float*)d_in[24];
  const float* Wd_s   = (const float*)d_in[25];
  const float* bd_s   = (const float*)d_in[26];
  const float* vd     = (const float*)d_in[27];
  const float* w_pg_em  = (const float*)d_in[28];
  const float* w_pg_cte = (const float*)d_in[29];
  const float* w_pg_ctd = (const float*)d_in[30];
  const float* w_pg_st  = (const float*)d_in[31];
  const float* b_pg_st  = (const float*)d_in[32];
  const float* W_V    = (const float*)d_in[33];
  const float* b_V    = (const float*)d_in[34];
  const float* W_V1   = (const float*)d_in[35];
  const float* b_V1   = (const float*)d_in[36];
  (void)in_sizes; (void)n_in; (void)out_size; (void)ws_size;

  float* out = (float*)d_out;
  float* o_final = out;
  float* o_h     = out + 3206400;
  float* o_c     = out + 3239168;
  float* o_cte   = out + 3271936;
  float* o_au    = out + 3337472;
  float* o_et2   = out + 3363072;
  float* o_sumn  = out + 3428608;
  float* o_prevs = out + 3454208;

  char* ws = (char*)d_ws;
  // zeroed accumulators
  float* et_raw    = (float*)(ws + 0);
  float* au_raw    = (float*)(ws + 102400);
  float* et2_acc   = (float*)(ws + 204800);
  float* x_acc     = (float*)(ws + 466944);
  float* gates_acc = (float*)(ws + 532480);
  float* qe_acc    = (float*)(ws + 1056768);
  float* qd_acc    = (float*)(ws + 1318912);
  float* ov_acc    = (float*)(ws + 1449984);    // end 1581056
  // scratch
  float* at_ws   = (float*)(ws + 1581056);
  float* ct_d    = (float*)(ws + 1683456);
  float* p_gen   = (float*)(ws + 1814528);
  float* tmp_ed  = (float*)(ws + 1900544);      // 6.55 MB (shares region with logits)
  float* logits  = (float*)(ws + 1900544);      // 12.8 MB -> end 14700544
  unsigned short* enc_bf  = (unsigned short*)(ws + 14780416);   // 52.4 MB
  unsigned short* Bt_bf   = (unsigned short*)(ws + 67209216);   // 4 MB
  // softmax partials alias the (already-consumed) gemv accumulator region
  float* mpart = (float*)(ws + 466944);         // 64*782*4 = 200192 B
  float* spart = (float*)(ws + 667136);         // 200192 B -> end 867328

  hipMemsetAsync(ws, 0, 1581056, stream);
  k_conv_enc<<<27648, 256, 0, stream>>>(enc, enc_bf, We_h, Ws_h, Bt_bf);
  k_gemv_x<<<dim3(1,64,5), 256, 0, stream>>>(x_t, ct_e, W_xc, x_acc);
  k_gemv_gates<<<dim3(8,64,3), 256, 0, stream>>>(x_acc, b_xc, s_h, W_ih, W_hh, gates_acc);
  k_lstm_act<<<dim3(2,64), 256, 0, stream>>>(gates_acc, b_ih, b_hh, s_c, o_h, o_c);
  k_qqp<<<7808, 256, 0, stream>>>(o_h, o_c, We_s, qe_acc, Wd_s, qd_acc, prev_s, o_prevs);
  k_gemm_big<<<3456, 256, 0, stream>>>(enc_bf, Bt_bf, qe_acc, be_s, bs_h, ve, vs1, vs2,
                                       et_raw, au_raw, et2_acc,
                                       prev_s, Wd_prev, qd_acc, bd_s, vd, tmp_ed);
  k_attn_norm<<<64, 512, 0, stream>>>(et_raw, au_raw, et2_acc, sumts, mask, o_sumn, o_au, o_et2, at_ws);
  k_cte<<<dim3(2,64), 256, 0, stream>>>(enc_bf, at_ws, o_cte);
  k_ctd_pgen<<<64, 512, 0, stream>>>(tmp_ed, prev_s, o_cte, o_et2, o_h, o_c,
                                     w_pg_cte, w_pg_ctd, w_pg_st, w_pg_em, b_pg_st, ct_d, p_gen);
  k_gemv_outvec<<<dim3(2,64,6), 256, 0, stream>>>(o_h, o_cte, ct_d, o_et2, W_V, ov_acc);
  k_logits_mfma<<<782, 256, 0, stream>>>(ov_acc, b_V, W_V1, b_V1, logits, mpart, spart);
  k_softmax_write<<<dim3(8,64), 1024, 0, stream>>>(logits, mpart, spart, p_gen, o_final);
  k_scatter_add<<<64, 512, 0, stream>>>(p_gen, ebev, at_ws, o_final);
}